// Round 1
// baseline (508.359 us; speedup 1.0000x reference)
//
#include <hip/hip_runtime.h>
#include <hip/hip_bf16.h>

#define B 2048
#define NH 8
#define HD 64
#define DIM 512
#define QKVN 1536
#define ATTN_ELEMS ((size_t)NH * B * B)     // 33,554,432
#define OUT0_ELEMS ((size_t)B * DIM)        // 1,048,576

// ---------------------------------------------------------------------------
// K1: qkv = x @ W_qkv   [2048,512] @ [512,1536]
// ---------------------------------------------------------------------------
__global__ __launch_bounds__(256) void gemm_qkv(const float* __restrict__ x,
                                                const float* __restrict__ w,
                                                float* __restrict__ qkv) {
    int nt = blockIdx.x;   // 0..23
    int mt = blockIdx.y;   // 0..31
    __shared__ float As[32][68];   // [kk][row]
    __shared__ float Bs[32][68];   // [kk][col]
    int tid = threadIdx.x;
    int tx = tid % 16, ty = tid / 16;
    float acc[4][4] = {};
    for (int k0 = 0; k0 < 512; k0 += 32) {
        {
            int r = tid / 8;
            int c4 = (tid % 8) * 4;
#pragma unroll
            for (int p = 0; p < 2; ++p) {
                int rr = p * 32 + r;
                float4 a = *(const float4*)(x + (size_t)(mt * 64 + rr) * 512 + k0 + c4);
                As[c4 + 0][rr] = a.x; As[c4 + 1][rr] = a.y;
                As[c4 + 2][rr] = a.z; As[c4 + 3][rr] = a.w;
            }
            int br = tid / 16;
            int bc4 = (tid % 16) * 4;
#pragma unroll
            for (int p = 0; p < 2; ++p) {
                int rr = p * 16 + br;
                *(float4*)&Bs[rr][bc4] = *(const float4*)(w + (size_t)(k0 + rr) * QKVN + nt * 64 + bc4);
            }
        }
        __syncthreads();
#pragma unroll 8
        for (int kk = 0; kk < 32; ++kk) {
            float4 av = *(const float4*)&As[kk][ty * 4];
            float4 bv = *(const float4*)&Bs[kk][tx * 4];
            const float* ap = &av.x;
            const float* bp = &bv.x;
#pragma unroll
            for (int i = 0; i < 4; ++i)
#pragma unroll
                for (int j = 0; j < 4; ++j) acc[i][j] += ap[i] * bp[j];
        }
        __syncthreads();
    }
#pragma unroll
    for (int i = 0; i < 4; ++i) {
        float4 c = make_float4(acc[i][0], acc[i][1], acc[i][2], acc[i][3]);
        *(float4*)(qkv + (size_t)(mt * 64 + ty * 4 + i) * QKVN + nt * 64 + tx * 4) = c;
    }
}

// ---------------------------------------------------------------------------
// K2: E = exp(q @ k^T * scale) (unnormalized), accumulate rowsum
// ---------------------------------------------------------------------------
__global__ __launch_bounds__(256) void logits_exp(const float* __restrict__ qkv,
                                                  float* __restrict__ attn,
                                                  float* __restrict__ rowsum) {
    int kt = blockIdx.x, qt = blockIdx.y, h = blockIdx.z;
    __shared__ float Qs[64][68];   // [d][q]
    __shared__ float Ks[64][68];   // [d][k]
    int tid = threadIdx.x;
    {
        const float* qbase = qkv + (size_t)(qt * 64) * QKVN + h * 64;
        const float* kbase = qkv + (size_t)(kt * 64) * QKVN + 512 + h * 64;
        int r = tid / 16;
        int c4 = (tid % 16) * 4;
#pragma unroll
        for (int p = 0; p < 4; ++p) {
            int rr = p * 16 + r;
            float4 a = *(const float4*)(qbase + (size_t)rr * QKVN + c4);
            Qs[c4 + 0][rr] = a.x; Qs[c4 + 1][rr] = a.y;
            Qs[c4 + 2][rr] = a.z; Qs[c4 + 3][rr] = a.w;
            float4 b = *(const float4*)(kbase + (size_t)rr * QKVN + c4);
            Ks[c4 + 0][rr] = b.x; Ks[c4 + 1][rr] = b.y;
            Ks[c4 + 2][rr] = b.z; Ks[c4 + 3][rr] = b.w;
        }
    }
    __syncthreads();
    int tx = tid % 16, ty = tid / 16;
    float acc[4][4] = {};
#pragma unroll 16
    for (int kk = 0; kk < 64; ++kk) {
        float4 qv = *(const float4*)&Qs[kk][ty * 4];
        float4 kv = *(const float4*)&Ks[kk][tx * 4];
        const float* qp = &qv.x;
        const float* kp = &kv.x;
#pragma unroll
        for (int i = 0; i < 4; ++i)
#pragma unroll
            for (int j = 0; j < 4; ++j) acc[i][j] += qp[i] * kp[j];
    }
    float rs[4];
    size_t base = (size_t)h * B * B + (size_t)(qt * 64) * B + kt * 64;
#pragma unroll
    for (int i = 0; i < 4; ++i) {
        float4 e;
        e.x = __expf(acc[i][0] * 0.125f);
        e.y = __expf(acc[i][1] * 0.125f);
        e.z = __expf(acc[i][2] * 0.125f);
        e.w = __expf(acc[i][3] * 0.125f);
        *(float4*)(attn + base + (size_t)(ty * 4 + i) * B + tx * 4) = e;
        rs[i] = e.x + e.y + e.z + e.w;
    }
#pragma unroll
    for (int i = 0; i < 4; ++i) {
        float s = rs[i];
        s += __shfl_xor(s, 1); s += __shfl_xor(s, 2);
        s += __shfl_xor(s, 4); s += __shfl_xor(s, 8);
        if (tx == 0) atomicAdd(&rowsum[h * B + qt * 64 + ty * 4 + i], s);
    }
}

// ---------------------------------------------------------------------------
// K3: attn[h,q,k] /= rowsum[h,q]; colsum[h,k] += attn
// tile: 64 rows x 128 cols
// ---------------------------------------------------------------------------
__global__ __launch_bounds__(256) void norm_colsum(float* __restrict__ attn,
                                                   const float* __restrict__ rowsum,
                                                   float* __restrict__ colsum) {
    int ct = blockIdx.x;   // 0..15
    int rt = blockIdx.y;   // 0..31
    int h = blockIdx.z;
    int tid = threadIdx.x;
    int cg = tid % 32;
    int rg = tid / 32;
    size_t base = (size_t)h * B * B + (size_t)(rt * 64) * B + ct * 128 + cg * 4;
    const float* rsp = rowsum + h * B + rt * 64;
    float a0 = 0, a1 = 0, a2 = 0, a3 = 0;
#pragma unroll
    for (int rr = 0; rr < 8; ++rr) {
        int r = rg + rr * 8;
        float rinv = 1.0f / rsp[r];
        float4 v = *(float4*)(attn + base + (size_t)r * B);
        v.x *= rinv; v.y *= rinv; v.z *= rinv; v.w *= rinv;
        *(float4*)(attn + base + (size_t)r * B) = v;
        a0 += v.x; a1 += v.y; a2 += v.z; a3 += v.w;
    }
    __shared__ float cs[128];
    if (tid < 128) cs[tid] = 0.f;
    __syncthreads();
    atomicAdd(&cs[cg * 4 + 0], a0);
    atomicAdd(&cs[cg * 4 + 1], a1);
    atomicAdd(&cs[cg * 4 + 2], a2);
    atomicAdd(&cs[cg * 4 + 3], a3);
    __syncthreads();
    if (tid < 128) atomicAdd(&colsum[h * B + ct * 128 + tid], cs[tid]);
}

// ---------------------------------------------------------------------------
// K4: top-5 columns per head by colsum
// ---------------------------------------------------------------------------
__global__ __launch_bounds__(256) void topk5(const float* __restrict__ colsum,
                                             int* __restrict__ topidx) {
    int h = blockIdx.x;
    __shared__ float v[B];
    __shared__ float bv[256];
    __shared__ int bi[256];
    int tid = threadIdx.x;
    for (int i = tid; i < B; i += 256) v[i] = colsum[h * B + i];
    __syncthreads();
    for (int it = 0; it < 5; ++it) {
        float best = -1e30f;
        int bidx = 0;
        for (int i = tid; i < B; i += 256) {
            float x = v[i];
            if (x > best || (x == best && i < bidx)) { best = x; bidx = i; }
        }
        bv[tid] = best; bi[tid] = bidx;
        __syncthreads();
        for (int s = 128; s > 0; s >>= 1) {
            if (tid < s) {
                if (bv[tid + s] > bv[tid] ||
                    (bv[tid + s] == bv[tid] && bi[tid + s] < bi[tid])) {
                    bv[tid] = bv[tid + s]; bi[tid] = bi[tid + s];
                }
            }
            __syncthreads();
        }
        if (tid == 0) { topidx[h * 8 + it] = bi[0]; v[bi[0]] = -1e30f; }
        __syncthreads();
    }
}

// ---------------------------------------------------------------------------
// K5: zero masked columns
// ---------------------------------------------------------------------------
__global__ __launch_bounds__(256) void mask_cols(float* __restrict__ attn,
                                                 const int* __restrict__ topidx) {
    int t = blockIdx.x * 256 + threadIdx.x;   // 8*5*2048
    if (t >= NH * 5 * B) return;
    int h = t / (5 * B);
    int rem = t % (5 * B);
    int i = rem / B;
    int q = rem % B;
    int k = topidx[h * 8 + i];
    attn[(size_t)h * B * B + (size_t)q * B + k] = 0.f;
}

// ---------------------------------------------------------------------------
// K6: ov = attn @ v   per head [2048,2048]@[2048,64]
// ---------------------------------------------------------------------------
__global__ __launch_bounds__(256) void pv_gemm(const float* __restrict__ attn,
                                               const float* __restrict__ qkv,
                                               float* __restrict__ ov) {
    int mt = blockIdx.x;   // 0..31
    int h = blockIdx.y;
    __shared__ float As[32][68];   // [kk][row]
    __shared__ float Bs[32][68];   // [kk][d]
    int tid = threadIdx.x;
    int tx = tid % 16, ty = tid / 16;
    float acc[4][4] = {};
    const float* vbase = qkv + 1024 + h * 64;
    size_t abase = (size_t)h * B * B + (size_t)(mt * 64) * B;
    for (int k0 = 0; k0 < B; k0 += 32) {
        {
            int r = tid / 8;
            int c4 = (tid % 8) * 4;
#pragma unroll
            for (int p = 0; p < 2; ++p) {
                int rr = p * 32 + r;
                float4 a = *(const float4*)(attn + abase + (size_t)rr * B + k0 + c4);
                As[c4 + 0][rr] = a.x; As[c4 + 1][rr] = a.y;
                As[c4 + 2][rr] = a.z; As[c4 + 3][rr] = a.w;
            }
            int br = tid / 16;
            int bc4 = (tid % 16) * 4;
#pragma unroll
            for (int p = 0; p < 2; ++p) {
                int rr = p * 16 + br;
                *(float4*)&Bs[rr][bc4] = *(const float4*)(vbase + (size_t)(k0 + rr) * QKVN + bc4);
            }
        }
        __syncthreads();
#pragma unroll 8
        for (int kk = 0; kk < 32; ++kk) {
            float4 av = *(const float4*)&As[kk][ty * 4];
            float4 bv = *(const float4*)&Bs[kk][tx * 4];
            const float* ap = &av.x;
            const float* bp = &bv.x;
#pragma unroll
            for (int i = 0; i < 4; ++i)
#pragma unroll
                for (int j = 0; j < 4; ++j) acc[i][j] += ap[i] * bp[j];
        }
        __syncthreads();
    }
#pragma unroll
    for (int i = 0; i < 4; ++i) {
        float4 c = make_float4(acc[i][0], acc[i][1], acc[i][2], acc[i][3]);
        *(float4*)(ov + (size_t)(mt * 64 + ty * 4 + i) * DIM + h * 64 + tx * 4) = c;
    }
}

// ---------------------------------------------------------------------------
// K7: y = ov @ W_proj^T + b_proj
// ---------------------------------------------------------------------------
__global__ __launch_bounds__(256) void proj_gemm(const float* __restrict__ ov,
                                                 const float* __restrict__ wproj,
                                                 const float* __restrict__ bproj,
                                                 float* __restrict__ y) {
    int nt = blockIdx.x;   // 0..7
    int mt = blockIdx.y;   // 0..31
    __shared__ float As[32][68];   // [kk][row]
    __shared__ float Bs[32][68];   // [kk][j]
    int tid = threadIdx.x;
    int tx = tid % 16, ty = tid / 16;
    float acc[4][4] = {};
    for (int k0 = 0; k0 < 512; k0 += 32) {
        {
            int r = tid / 8;
            int c4 = (tid % 8) * 4;
#pragma unroll
            for (int p = 0; p < 2; ++p) {
                int rr = p * 32 + r;
                float4 a = *(const float4*)(ov + (size_t)(mt * 64 + rr) * DIM + k0 + c4);
                As[c4 + 0][rr] = a.x; As[c4 + 1][rr] = a.y;
                As[c4 + 2][rr] = a.z; As[c4 + 3][rr] = a.w;
                float4 b = *(const float4*)(wproj + (size_t)(nt * 64 + rr) * DIM + k0 + c4);
                Bs[c4 + 0][rr] = b.x; Bs[c4 + 1][rr] = b.y;
                Bs[c4 + 2][rr] = b.z; Bs[c4 + 3][rr] = b.w;
            }
        }
        __syncthreads();
#pragma unroll 8
        for (int kk = 0; kk < 32; ++kk) {
            float4 av = *(const float4*)&As[kk][ty * 4];
            float4 bv = *(const float4*)&Bs[kk][tx * 4];
            const float* ap = &av.x;
            const float* bp = &bv.x;
#pragma unroll
            for (int i = 0; i < 4; ++i)
#pragma unroll
                for (int j = 0; j < 4; ++j) acc[i][j] += ap[i] * bp[j];
        }
        __syncthreads();
    }
#pragma unroll
    for (int i = 0; i < 4; ++i) {
        float4 c;
        c.x = acc[i][0] + bproj[nt * 64 + tx * 4 + 0];
        c.y = acc[i][1] + bproj[nt * 64 + tx * 4 + 1];
        c.z = acc[i][2] + bproj[nt * 64 + tx * 4 + 2];
        c.w = acc[i][3] + bproj[nt * 64 + tx * 4 + 3];
        *(float4*)(y + (size_t)(mt * 64 + ty * 4 + i) * DIM + nt * 64 + tx * 4) = c;
    }
}

// ---------------------------------------------------------------------------
// K8: BatchNorm stats (training mode, biased var) over batch axis
// ---------------------------------------------------------------------------
__global__ __launch_bounds__(256) void bn_stats(const float* __restrict__ y,
                                                float* __restrict__ mean_out,
                                                float* __restrict__ rstd_out) {
    int cbase = blockIdx.x * 64;
    int c = cbase + (threadIdx.x % 64);
    int rg = threadIdx.x / 64;   // 0..3
    float s = 0.f, ss = 0.f;
    for (int r = rg; r < B; r += 4) {
        float v = y[(size_t)r * DIM + c];
        s += v; ss += v * v;
    }
    __shared__ float Ss[4][64];
    __shared__ float SSs[4][64];
    Ss[rg][threadIdx.x % 64] = s;
    SSs[rg][threadIdx.x % 64] = ss;
    __syncthreads();
    if (threadIdx.x < 64) {
        int cc = threadIdx.x;
        float st = Ss[0][cc] + Ss[1][cc] + Ss[2][cc] + Ss[3][cc];
        float sst = SSs[0][cc] + SSs[1][cc] + SSs[2][cc] + SSs[3][cc];
        float m = st * (1.0f / B);
        float var = sst * (1.0f / B) - m * m;
        mean_out[cbase + cc] = m;
        rstd_out[cbase + cc] = rsqrtf(var + 1e-5f);
    }
}

// ---------------------------------------------------------------------------
// K9: out = relu(gamma*(y-mean)*rstd + beta)
// ---------------------------------------------------------------------------
__global__ __launch_bounds__(256) void bn_apply(const float* __restrict__ y,
                                                const float* __restrict__ mean,
                                                const float* __restrict__ rstd,
                                                const float* __restrict__ gamma,
                                                const float* __restrict__ beta,
                                                float* __restrict__ out) {
    int t = blockIdx.x * 256 + threadIdx.x;   // each handles float4
    int c4 = (t % 128) * 4;
    size_t r = t / 128;
    if (r >= B) return;
    float4 v = *(const float4*)(y + r * DIM + c4);
    float4 m = *(const float4*)(mean + c4);
    float4 rs = *(const float4*)(rstd + c4);
    float4 g = *(const float4*)(gamma + c4);
    float4 bt = *(const float4*)(beta + c4);
    float4 o;
    o.x = fmaxf(0.f, g.x * (v.x - m.x) * rs.x + bt.x);
    o.y = fmaxf(0.f, g.y * (v.y - m.y) * rs.y + bt.y);
    o.z = fmaxf(0.f, g.z * (v.z - m.z) * rs.z + bt.z);
    o.w = fmaxf(0.f, g.w * (v.w - m.w) * rs.w + bt.w);
    *(float4*)(out + r * DIM + c4) = o;
}

// ---------------------------------------------------------------------------
extern "C" void kernel_launch(void* const* d_in, const int* in_sizes, int n_in,
                              void* d_out, int out_size, void* d_ws, size_t ws_size,
                              hipStream_t stream) {
    const float* x = (const float*)d_in[0];
    const float* W_qkv = (const float*)d_in[1];
    const float* W_proj = (const float*)d_in[2];
    const float* b_proj = (const float*)d_in[3];
    const float* bn_gamma = (const float*)d_in[4];
    const float* bn_beta = (const float*)d_in[5];

    float* out0 = (float*)d_out;                         // [2048,512]
    float* attn = (float*)d_out + OUT0_ELEMS;            // [8,2048,2048]

    float* ws = (float*)d_ws;
    float* qkv = ws;                                     // 3,145,728
    float* ov = qkv + (size_t)B * QKVN;                  // 1,048,576
    float* y = ov + OUT0_ELEMS;                          // 1,048,576
    float* rowsum = y + OUT0_ELEMS;                      // 16,384
    float* colsum = rowsum + NH * B;                     // 16,384
    float* bn_mean = colsum + NH * B;                    // 512
    float* bn_rstd = bn_mean + DIM;                      // 512
    int* topidx = (int*)(bn_rstd + DIM);                 // 64 ints

    hipMemsetAsync(rowsum, 0, NH * B * sizeof(float), stream);
    hipMemsetAsync(colsum, 0, NH * B * sizeof(float), stream);

    gemm_qkv<<<dim3(QKVN / 64, B / 64), 256, 0, stream>>>(x, W_qkv, qkv);
    logits_exp<<<dim3(B / 64, B / 64, NH), 256, 0, stream>>>(qkv, attn, rowsum);
    norm_colsum<<<dim3(B / 128, B / 64, NH), 256, 0, stream>>>(attn, rowsum, colsum);
    topk5<<<NH, 256, 0, stream>>>(colsum, topidx);
    mask_cols<<<(NH * 5 * B + 255) / 256, 256, 0, stream>>>(attn, topidx);
    pv_gemm<<<dim3(B / 64, NH), 256, 0, stream>>>(attn, qkv, ov);
    proj_gemm<<<dim3(DIM / 64, B / 64), 256, 0, stream>>>(ov, W_proj, b_proj, y);
    bn_stats<<<DIM / 64, 256, 0, stream>>>(y, bn_mean, bn_rstd);
    bn_apply<<<(B * DIM / 4 + 255) / 256, 256, 0, stream>>>(y, bn_mean, bn_rstd,
                                                            bn_gamma, bn_beta, out0);
}

// Round 2
// 404.876 us; speedup vs baseline: 1.2556x; 1.2556x over previous
//
#include <hip/hip_runtime.h>
#include <hip/hip_bf16.h>

#define B 2048
#define NH 8
#define HD 64
#define DIM 512
#define QKVN 1536
#define ATTN_ELEMS ((size_t)NH * B * B)     // 33,554,432
#define OUT0_ELEMS ((size_t)B * DIM)        // 1,048,576

// ---------------------------------------------------------------------------
// K1: qkv = x @ W_qkv   [2048,512] @ [512,1536]
// ---------------------------------------------------------------------------
__global__ __launch_bounds__(256) void gemm_qkv(const float* __restrict__ x,
                                                const float* __restrict__ w,
                                                float* __restrict__ qkv) {
    int nt = blockIdx.x;   // 0..23
    int mt = blockIdx.y;   // 0..31
    __shared__ float As[32][68];   // [kk][row]
    __shared__ float Bs[32][68];   // [kk][col]
    int tid = threadIdx.x;
    int tx = tid % 16, ty = tid / 16;
    float acc[4][4] = {};
    for (int k0 = 0; k0 < 512; k0 += 32) {
        {
            int r = tid / 8;
            int c4 = (tid % 8) * 4;
#pragma unroll
            for (int p = 0; p < 2; ++p) {
                int rr = p * 32 + r;
                float4 a = *(const float4*)(x + (size_t)(mt * 64 + rr) * 512 + k0 + c4);
                As[c4 + 0][rr] = a.x; As[c4 + 1][rr] = a.y;
                As[c4 + 2][rr] = a.z; As[c4 + 3][rr] = a.w;
            }
            int br = tid / 16;
            int bc4 = (tid % 16) * 4;
#pragma unroll
            for (int p = 0; p < 2; ++p) {
                int rr = p * 16 + br;
                *(float4*)&Bs[rr][bc4] = *(const float4*)(w + (size_t)(k0 + rr) * QKVN + nt * 64 + bc4);
            }
        }
        __syncthreads();
#pragma unroll 8
        for (int kk = 0; kk < 32; ++kk) {
            float4 av = *(const float4*)&As[kk][ty * 4];
            float4 bv = *(const float4*)&Bs[kk][tx * 4];
            const float* ap = &av.x;
            const float* bp = &bv.x;
#pragma unroll
            for (int i = 0; i < 4; ++i)
#pragma unroll
                for (int j = 0; j < 4; ++j) acc[i][j] += ap[i] * bp[j];
        }
        __syncthreads();
    }
#pragma unroll
    for (int i = 0; i < 4; ++i) {
        float4 c = make_float4(acc[i][0], acc[i][1], acc[i][2], acc[i][3]);
        *(float4*)(qkv + (size_t)(mt * 64 + ty * 4 + i) * QKVN + nt * 64 + tx * 4) = c;
    }
}

// ---------------------------------------------------------------------------
// K2: E = exp(q @ k^T * scale) (unnormalized), accumulate rowsum
// ---------------------------------------------------------------------------
__global__ __launch_bounds__(256) void logits_exp(const float* __restrict__ qkv,
                                                  float* __restrict__ attn,
                                                  float* __restrict__ rowsum) {
    int kt = blockIdx.x, qt = blockIdx.y, h = blockIdx.z;
    __shared__ float Qs[64][68];   // [d][q]
    __shared__ float Ks[64][68];   // [d][k]
    int tid = threadIdx.x;
    {
        const float* qbase = qkv + (size_t)(qt * 64) * QKVN + h * 64;
        const float* kbase = qkv + (size_t)(kt * 64) * QKVN + 512 + h * 64;
        int r = tid / 16;
        int c4 = (tid % 16) * 4;
#pragma unroll
        for (int p = 0; p < 4; ++p) {
            int rr = p * 16 + r;
            float4 a = *(const float4*)(qbase + (size_t)rr * QKVN + c4);
            Qs[c4 + 0][rr] = a.x; Qs[c4 + 1][rr] = a.y;
            Qs[c4 + 2][rr] = a.z; Qs[c4 + 3][rr] = a.w;
            float4 b = *(const float4*)(kbase + (size_t)rr * QKVN + c4);
            Ks[c4 + 0][rr] = b.x; Ks[c4 + 1][rr] = b.y;
            Ks[c4 + 2][rr] = b.z; Ks[c4 + 3][rr] = b.w;
        }
    }
    __syncthreads();
    int tx = tid % 16, ty = tid / 16;
    float acc[4][4] = {};
#pragma unroll 16
    for (int kk = 0; kk < 64; ++kk) {
        float4 qv = *(const float4*)&Qs[kk][ty * 4];
        float4 kv = *(const float4*)&Ks[kk][tx * 4];
        const float* qp = &qv.x;
        const float* kp = &kv.x;
#pragma unroll
        for (int i = 0; i < 4; ++i)
#pragma unroll
            for (int j = 0; j < 4; ++j) acc[i][j] += qp[i] * kp[j];
    }
    float rs[4];
    size_t base = (size_t)h * B * B + (size_t)(qt * 64) * B + kt * 64;
#pragma unroll
    for (int i = 0; i < 4; ++i) {
        float4 e;
        e.x = __expf(acc[i][0] * 0.125f);
        e.y = __expf(acc[i][1] * 0.125f);
        e.z = __expf(acc[i][2] * 0.125f);
        e.w = __expf(acc[i][3] * 0.125f);
        *(float4*)(attn + base + (size_t)(ty * 4 + i) * B + tx * 4) = e;
        rs[i] = e.x + e.y + e.z + e.w;
    }
#pragma unroll
    for (int i = 0; i < 4; ++i) {
        float s = rs[i];
        s += __shfl_xor(s, 1); s += __shfl_xor(s, 2);
        s += __shfl_xor(s, 4); s += __shfl_xor(s, 8);
        if (tx == 0) atomicAdd(&rowsum[h * B + qt * 64 + ty * 4 + i], s);
    }
}

// ---------------------------------------------------------------------------
// K3 (fused): attn = E/rowsum (write back), colsum += attn,
//             ovp[ct] = P_chunk @ V_chunk  (full PV, unmasked, split-K by ct)
// grid: (4 col-chunks of 512, 32 row-tiles of 64, 8 heads), 256 threads
// ---------------------------------------------------------------------------
__global__ __launch_bounds__(256) void norm_colsum_pv(float* __restrict__ attn,
                                                      const float* __restrict__ qkv,
                                                      const float* __restrict__ rowsum,
                                                      float* __restrict__ colsum,
                                                      float* __restrict__ ovp) {
    int ct = blockIdx.x;   // 0..3
    int rt = blockIdx.y;   // 0..31
    int h = blockIdx.z;
    int tid = threadIdx.x;
    int lane = tid & 63;
    __shared__ float As[32][68];   // [kk][q]  normalized P (transposed)
    __shared__ float Bs[32][68];   // [kk][d]  V
    __shared__ float cs[512];      // per-block colsum partials
    __shared__ float rinv_s[64];
    if (tid < 64) rinv_s[tid] = 1.0f / rowsum[h * B + rt * 64 + tid];
    for (int i = tid; i < 512; i += 256) cs[i] = 0.f;
    __syncthreads();

    int tx = tid % 16, ty = tid / 16;
    int r = tid / 8;          // 0..31
    int c4 = (tid % 8) * 4;   // 0..28
    float acc[4][4] = {};
    size_t abase = (size_t)h * B * B + (size_t)(rt * 64) * B + ct * 512;
    const float* vbase = qkv + 1024 + h * 64;

    for (int s = 0; s < 16; ++s) {
        // --- stage P tile (read E, normalize, write back, transpose to LDS) ---
        float cp[4] = {0.f, 0.f, 0.f, 0.f};
#pragma unroll
        for (int p = 0; p < 2; ++p) {
            int rr = p * 32 + r;
            float rv = rinv_s[rr];
            size_t idx = abase + (size_t)rr * B + s * 32 + c4;
            float4 v = *(const float4*)(attn + idx);
            v.x *= rv; v.y *= rv; v.z *= rv; v.w *= rv;
            *(float4*)(attn + idx) = v;
            As[c4 + 0][rr] = v.x; As[c4 + 1][rr] = v.y;
            As[c4 + 2][rr] = v.z; As[c4 + 3][rr] = v.w;
            cp[0] += v.x; cp[1] += v.y; cp[2] += v.z; cp[3] += v.w;
        }
        // --- stage V tile [32 k x 64 d] ---
        {
            int br = tid / 16;
            int bc4 = (tid % 16) * 4;
#pragma unroll
            for (int p = 0; p < 2; ++p) {
                int rr = p * 16 + br;
                *(float4*)&Bs[rr][bc4] =
                    *(const float4*)(vbase + (size_t)(ct * 512 + s * 32 + rr) * QKVN + bc4);
            }
        }
        // --- colsum: reduce over the 8 row-lanes sharing a column group ---
#pragma unroll
        for (int j = 0; j < 4; ++j) {
            cp[j] += __shfl_xor(cp[j], 8);
            cp[j] += __shfl_xor(cp[j], 16);
            cp[j] += __shfl_xor(cp[j], 32);
        }
        if (lane < 8) {
#pragma unroll
            for (int j = 0; j < 4; ++j) atomicAdd(&cs[s * 32 + c4 + j], cp[j]);
        }
        __syncthreads();
        // --- PV microkernel over this 32-k slab ---
#pragma unroll 8
        for (int kk = 0; kk < 32; ++kk) {
            float4 av = *(const float4*)&As[kk][ty * 4];
            float4 bv = *(const float4*)&Bs[kk][tx * 4];
            const float* ap = &av.x;
            const float* bp = &bv.x;
#pragma unroll
            for (int i = 0; i < 4; ++i)
#pragma unroll
                for (int j = 0; j < 4; ++j) acc[i][j] += ap[i] * bp[j];
        }
        __syncthreads();
    }
    // flush colsum
    for (int i = tid; i < 512; i += 256)
        atomicAdd(&colsum[h * B + ct * 512 + i], cs[i]);
    // write PV partial (single writer per element)
#pragma unroll
    for (int i = 0; i < 4; ++i) {
        float4 c = make_float4(acc[i][0], acc[i][1], acc[i][2], acc[i][3]);
        *(float4*)(ovp + ((size_t)ct * B + rt * 64 + ty * 4 + i) * DIM + h * 64 + tx * 4) = c;
    }
}

// ---------------------------------------------------------------------------
// K4: top-5 columns per head by colsum
// ---------------------------------------------------------------------------
__global__ __launch_bounds__(256) void topk5(const float* __restrict__ colsum,
                                             int* __restrict__ topidx) {
    int h = blockIdx.x;
    __shared__ float v[B];
    __shared__ float bv[256];
    __shared__ int bi[256];
    int tid = threadIdx.x;
    for (int i = tid; i < B; i += 256) v[i] = colsum[h * B + i];
    __syncthreads();
    for (int it = 0; it < 5; ++it) {
        float best = -1e30f;
        int bidx = 0;
        for (int i = tid; i < B; i += 256) {
            float x = v[i];
            if (x > best || (x == best && i < bidx)) { best = x; bidx = i; }
        }
        bv[tid] = best; bi[tid] = bidx;
        __syncthreads();
        for (int s = 128; s > 0; s >>= 1) {
            if (tid < s) {
                if (bv[tid + s] > bv[tid] ||
                    (bv[tid + s] == bv[tid] && bi[tid + s] < bi[tid])) {
                    bv[tid] = bv[tid + s]; bi[tid] = bi[tid + s];
                }
            }
            __syncthreads();
        }
        if (tid == 0) { topidx[h * 8 + it] = bi[0]; v[bi[0]] = -1e30f; }
        __syncthreads();
    }
}

// ---------------------------------------------------------------------------
// K5: maskfix — reduce ovp partials, subtract top-5 column correction,
//     zero the masked attn columns. grid (32 rt, 8 h)
// ---------------------------------------------------------------------------
__global__ __launch_bounds__(256) void maskfix(float* __restrict__ attn,
                                               const float* __restrict__ qkv,
                                               const int* __restrict__ topidx,
                                               const float* __restrict__ ovp,
                                               float* __restrict__ ov) {
    int rt = blockIdx.x;
    int h = blockIdx.y;
    int tid = threadIdx.x;
    __shared__ float Pl[5][64];
    __shared__ float Vl[5][64];
    __shared__ int tix[5];
    if (tid < 5) tix[tid] = topidx[h * 8 + tid];
    __syncthreads();
    size_t abase = (size_t)h * B * B + (size_t)(rt * 64) * B;
    for (int t = tid; t < 320; t += 256) {
        int i = t / 64, q = t % 64;
        Pl[i][q] = attn[abase + (size_t)q * B + tix[i]];
        Vl[i][q] = qkv[(size_t)tix[i] * QKVN + 1024 + h * 64 + q];
    }
    __syncthreads();
    // zero masked columns (this block's rows only)
    for (int t = tid; t < 320; t += 256) {
        int i = t / 64, q = t % 64;
        attn[abase + (size_t)q * B + tix[i]] = 0.f;
    }
    int tx = tid % 16, ty = tid / 16;
    float corr[4][4] = {};
#pragma unroll
    for (int i = 0; i < 5; ++i)
#pragma unroll
        for (int a = 0; a < 4; ++a)
#pragma unroll
            for (int b2 = 0; b2 < 4; ++b2)
                corr[a][b2] += Pl[i][ty * 4 + a] * Vl[i][tx * 4 + b2];
#pragma unroll
    for (int a = 0; a < 4; ++a) {
        size_t row = (size_t)(rt * 64 + ty * 4 + a);
        size_t col = h * 64 + tx * 4;
        float4 s0 = *(const float4*)(ovp + ((size_t)0 * B + row) * DIM + col);
        float4 s1 = *(const float4*)(ovp + ((size_t)1 * B + row) * DIM + col);
        float4 s2 = *(const float4*)(ovp + ((size_t)2 * B + row) * DIM + col);
        float4 s3 = *(const float4*)(ovp + ((size_t)3 * B + row) * DIM + col);
        float4 o;
        o.x = s0.x + s1.x + s2.x + s3.x - corr[a][0];
        o.y = s0.y + s1.y + s2.y + s3.y - corr[a][1];
        o.z = s0.z + s1.z + s2.z + s3.z - corr[a][2];
        o.w = s0.w + s1.w + s2.w + s3.w - corr[a][3];
        *(float4*)(ov + row * DIM + col) = o;
    }
}

// ---------------------------------------------------------------------------
// K7: y = ov @ W_proj^T + b_proj
// ---------------------------------------------------------------------------
__global__ __launch_bounds__(256) void proj_gemm(const float* __restrict__ ov,
                                                 const float* __restrict__ wproj,
                                                 const float* __restrict__ bproj,
                                                 float* __restrict__ y) {
    int nt = blockIdx.x;   // 0..7
    int mt = blockIdx.y;   // 0..31
    __shared__ float As[32][68];   // [kk][row]
    __shared__ float Bs[32][68];   // [kk][j]
    int tid = threadIdx.x;
    int tx = tid % 16, ty = tid / 16;
    float acc[4][4] = {};
    for (int k0 = 0; k0 < 512; k0 += 32) {
        {
            int r = tid / 8;
            int c4 = (tid % 8) * 4;
#pragma unroll
            for (int p = 0; p < 2; ++p) {
                int rr = p * 32 + r;
                float4 a = *(const float4*)(ov + (size_t)(mt * 64 + rr) * DIM + k0 + c4);
                As[c4 + 0][rr] = a.x; As[c4 + 1][rr] = a.y;
                As[c4 + 2][rr] = a.z; As[c4 + 3][rr] = a.w;
                float4 b = *(const float4*)(wproj + (size_t)(nt * 64 + rr) * DIM + k0 + c4);
                Bs[c4 + 0][rr] = b.x; Bs[c4 + 1][rr] = b.y;
                Bs[c4 + 2][rr] = b.z; Bs[c4 + 3][rr] = b.w;
            }
        }
        __syncthreads();
#pragma unroll 8
        for (int kk = 0; kk < 32; ++kk) {
            float4 av = *(const float4*)&As[kk][ty * 4];
            float4 bv = *(const float4*)&Bs[kk][tx * 4];
            const float* ap = &av.x;
            const float* bp = &bv.x;
#pragma unroll
            for (int i = 0; i < 4; ++i)
#pragma unroll
                for (int j = 0; j < 4; ++j) acc[i][j] += ap[i] * bp[j];
        }
        __syncthreads();
    }
#pragma unroll
    for (int i = 0; i < 4; ++i) {
        float4 c;
        c.x = acc[i][0] + bproj[nt * 64 + tx * 4 + 0];
        c.y = acc[i][1] + bproj[nt * 64 + tx * 4 + 1];
        c.z = acc[i][2] + bproj[nt * 64 + tx * 4 + 2];
        c.w = acc[i][3] + bproj[nt * 64 + tx * 4 + 3];
        *(float4*)(y + (size_t)(mt * 64 + ty * 4 + i) * DIM + nt * 64 + tx * 4) = c;
    }
}

// ---------------------------------------------------------------------------
// K8: BatchNorm stats (training mode, biased var) over batch axis
// ---------------------------------------------------------------------------
__global__ __launch_bounds__(256) void bn_stats(const float* __restrict__ y,
                                                float* __restrict__ mean_out,
                                                float* __restrict__ rstd_out) {
    int cbase = blockIdx.x * 64;
    int c = cbase + (threadIdx.x % 64);
    int rg = threadIdx.x / 64;   // 0..3
    float s = 0.f, ss = 0.f;
    for (int r = rg; r < B; r += 4) {
        float v = y[(size_t)r * DIM + c];
        s += v; ss += v * v;
    }
    __shared__ float Ss[4][64];
    __shared__ float SSs[4][64];
    Ss[rg][threadIdx.x % 64] = s;
    SSs[rg][threadIdx.x % 64] = ss;
    __syncthreads();
    if (threadIdx.x < 64) {
        int cc = threadIdx.x;
        float st = Ss[0][cc] + Ss[1][cc] + Ss[2][cc] + Ss[3][cc];
        float sst = SSs[0][cc] + SSs[1][cc] + SSs[2][cc] + SSs[3][cc];
        float m = st * (1.0f / B);
        float var = sst * (1.0f / B) - m * m;
        mean_out[cbase + cc] = m;
        rstd_out[cbase + cc] = rsqrtf(var + 1e-5f);
    }
}

// ---------------------------------------------------------------------------
// K9: out = relu(gamma*(y-mean)*rstd + beta)
// ---------------------------------------------------------------------------
__global__ __launch_bounds__(256) void bn_apply(const float* __restrict__ y,
                                                const float* __restrict__ mean,
                                                const float* __restrict__ rstd,
                                                const float* __restrict__ gamma,
                                                const float* __restrict__ beta,
                                                float* __restrict__ out) {
    int t = blockIdx.x * 256 + threadIdx.x;   // each handles float4
    int c4 = (t % 128) * 4;
    size_t r = t / 128;
    if (r >= B) return;
    float4 v = *(const float4*)(y + r * DIM + c4);
    float4 m = *(const float4*)(mean + c4);
    float4 rs = *(const float4*)(rstd + c4);
    float4 g = *(const float4*)(gamma + c4);
    float4 bt = *(const float4*)(beta + c4);
    float4 o;
    o.x = fmaxf(0.f, g.x * (v.x - m.x) * rs.x + bt.x);
    o.y = fmaxf(0.f, g.y * (v.y - m.y) * rs.y + bt.y);
    o.z = fmaxf(0.f, g.z * (v.z - m.z) * rs.z + bt.z);
    o.w = fmaxf(0.f, g.w * (v.w - m.w) * rs.w + bt.w);
    *(float4*)(out + r * DIM + c4) = o;
}

// ---------------------------------------------------------------------------
extern "C" void kernel_launch(void* const* d_in, const int* in_sizes, int n_in,
                              void* d_out, int out_size, void* d_ws, size_t ws_size,
                              hipStream_t stream) {
    const float* x = (const float*)d_in[0];
    const float* W_qkv = (const float*)d_in[1];
    const float* W_proj = (const float*)d_in[2];
    const float* b_proj = (const float*)d_in[3];
    const float* bn_gamma = (const float*)d_in[4];
    const float* bn_beta = (const float*)d_in[5];

    float* out0 = (float*)d_out;                         // [2048,512]
    float* attn = (float*)d_out + OUT0_ELEMS;            // [8,2048,2048]

    float* ws = (float*)d_ws;
    float* qkv = ws;                                     // 3,145,728
    float* ovp = qkv + (size_t)B * QKVN;                 // 4 * 1,048,576
    float* ov = ovp + 4 * OUT0_ELEMS;                    // 1,048,576
    float* y = ov + OUT0_ELEMS;                          // 1,048,576
    float* rowsum = y + OUT0_ELEMS;                      // 16,384
    float* colsum = rowsum + NH * B;                     // 16,384
    float* bn_mean = colsum + NH * B;                    // 512
    float* bn_rstd = bn_mean + DIM;                      // 512
    int* topidx = (int*)(bn_rstd + DIM);                 // 64 ints

    hipMemsetAsync(rowsum, 0, NH * B * sizeof(float), stream);
    hipMemsetAsync(colsum, 0, NH * B * sizeof(float), stream);

    gemm_qkv<<<dim3(QKVN / 64, B / 64), 256, 0, stream>>>(x, W_qkv, qkv);
    logits_exp<<<dim3(B / 64, B / 64, NH), 256, 0, stream>>>(qkv, attn, rowsum);
    norm_colsum_pv<<<dim3(4, B / 64, NH), 256, 0, stream>>>(attn, qkv, rowsum, colsum, ovp);
    topk5<<<NH, 256, 0, stream>>>(colsum, topidx);
    maskfix<<<dim3(B / 64, NH), 256, 0, stream>>>(attn, qkv, topidx, ovp, ov);
    proj_gemm<<<dim3(DIM / 64, B / 64), 256, 0, stream>>>(ov, W_proj, b_proj, y);
    bn_stats<<<DIM / 64, 256, 0, stream>>>(y, bn_mean, bn_rstd);
    bn_apply<<<(B * DIM / 4 + 255) / 256, 256, 0, stream>>>(y, bn_mean, bn_rstd,
                                                            bn_gamma, bn_beta, out0);
}

// Round 3
// 240.673 us; speedup vs baseline: 2.1122x; 1.6823x over previous
//
#include <hip/hip_runtime.h>
#include <hip/hip_bf16.h>

#define B 2048
#define NH 8
#define HD 64
#define DIM 512
#define QKVN 1536
#define ATTN_ELEMS ((size_t)NH * B * B)     // 33,554,432
#define OUT0_ELEMS ((size_t)B * DIM)        // 1,048,576

typedef float f32x4 __attribute__((ext_vector_type(4)));
typedef __bf16 bf16x8 __attribute__((ext_vector_type(8)));

static __device__ __forceinline__ unsigned short f2bf(float f) {
    unsigned int u = __builtin_bit_cast(unsigned int, f);
    u += 0x7fffu + ((u >> 16) & 1u);   // RNE (no NaN handling; values are small)
    return (unsigned short)(u >> 16);
}

// ---------------------------------------------------------------------------
// K1: qkv = x @ W_qkv  [2048,512]@[512,1536]; also emit bf16 copy of q,k cols
// ---------------------------------------------------------------------------
__global__ __launch_bounds__(256) void gemm_qkv(const float* __restrict__ x,
                                                const float* __restrict__ w,
                                                float* __restrict__ qkv,
                                                unsigned short* __restrict__ qkbf) {
    int nt = blockIdx.x;   // 0..23
    int mt = blockIdx.y;   // 0..31
    __shared__ float As[32][68];
    __shared__ float Bs[32][68];
    int tid = threadIdx.x;
    int tx = tid % 16, ty = tid / 16;
    float acc[4][4] = {};
    for (int k0 = 0; k0 < 512; k0 += 32) {
        {
            int r = tid / 8;
            int c4 = (tid % 8) * 4;
#pragma unroll
            for (int p = 0; p < 2; ++p) {
                int rr = p * 32 + r;
                float4 a = *(const float4*)(x + (size_t)(mt * 64 + rr) * 512 + k0 + c4);
                As[c4 + 0][rr] = a.x; As[c4 + 1][rr] = a.y;
                As[c4 + 2][rr] = a.z; As[c4 + 3][rr] = a.w;
            }
            int br = tid / 16;
            int bc4 = (tid % 16) * 4;
#pragma unroll
            for (int p = 0; p < 2; ++p) {
                int rr = p * 16 + br;
                *(float4*)&Bs[rr][bc4] = *(const float4*)(w + (size_t)(k0 + rr) * QKVN + nt * 64 + bc4);
            }
        }
        __syncthreads();
#pragma unroll 8
        for (int kk = 0; kk < 32; ++kk) {
            float4 av = *(const float4*)&As[kk][ty * 4];
            float4 bv = *(const float4*)&Bs[kk][tx * 4];
            const float* ap = &av.x;
            const float* bp = &bv.x;
#pragma unroll
            for (int i = 0; i < 4; ++i)
#pragma unroll
                for (int j = 0; j < 4; ++j) acc[i][j] += ap[i] * bp[j];
        }
        __syncthreads();
    }
#pragma unroll
    for (int i = 0; i < 4; ++i) {
        float4 c = make_float4(acc[i][0], acc[i][1], acc[i][2], acc[i][3]);
        size_t row = (size_t)(mt * 64 + ty * 4 + i);
        *(float4*)(qkv + row * QKVN + nt * 64 + tx * 4) = c;
        if (nt < 16) {   // q,k columns 0..1023 -> bf16 side copy
            ushort4 u;
            u.x = f2bf(c.x); u.y = f2bf(c.y); u.z = f2bf(c.z); u.w = f2bf(c.w);
            *(ushort4*)(qkbf + row * 1024 + nt * 64 + tx * 4) = u;
        }
    }
}

// ---------------------------------------------------------------------------
// K2: E = exp(q@k^T * scale) via bf16 MFMA; accumulate rowsum.
// 128x128 tile, 4 waves each 64x64. XOR-swizzled LDS (G4).
// ---------------------------------------------------------------------------
__global__ __launch_bounds__(256) void logits_mfma(const unsigned short* __restrict__ qkbf,
                                                   float* __restrict__ attn,
                                                   float* __restrict__ rowsum) {
    int kt = blockIdx.x, qt = blockIdx.y, h = blockIdx.z;
    __shared__ uint4 Qs[1024];   // 128 rows x 8 slots(16B), swizzled
    __shared__ uint4 Ks[1024];
    int tid = threadIdx.x;
    int l = tid & 63;
    int wid = tid >> 6;
    int wr = wid >> 1, wc = wid & 1;
    const uint4* qk4 = (const uint4*)qkbf;   // row stride 128 uint4
    {
#pragma unroll
        for (int it = 0; it < 4; ++it) {
            int chunk = it * 256 + tid;
            int row = chunk >> 3, slot = chunk & 7;
            int sw = slot ^ (row & 7);
            Qs[row * 8 + sw] = qk4[(size_t)(qt * 128 + row) * 128 + h * 8 + slot];
            Ks[row * 8 + sw] = qk4[(size_t)(kt * 128 + row) * 128 + 64 + h * 8 + slot];
        }
    }
    __syncthreads();
    f32x4 acc[4][4];
#pragma unroll
    for (int i = 0; i < 4; ++i)
#pragma unroll
        for (int j = 0; j < 4; ++j) acc[i][j] = (f32x4){0.f, 0.f, 0.f, 0.f};
#pragma unroll
    for (int ks = 0; ks < 2; ++ks) {
        bf16x8 aq[4], bk[4];
        int slot = ks * 4 + (l >> 4);
#pragma unroll
        for (int f = 0; f < 4; ++f) {
            int qrow = wr * 64 + f * 16 + (l & 15);
            aq[f] = __builtin_bit_cast(bf16x8, Qs[qrow * 8 + (slot ^ (qrow & 7))]);
            int krow = wc * 64 + f * 16 + (l & 15);
            bk[f] = __builtin_bit_cast(bf16x8, Ks[krow * 8 + (slot ^ (krow & 7))]);
        }
#pragma unroll
        for (int i = 0; i < 4; ++i)
#pragma unroll
            for (int j = 0; j < 4; ++j)
                acc[i][j] = __builtin_amdgcn_mfma_f32_16x16x32_bf16(aq[i], bk[j], acc[i][j], 0, 0, 0);
    }
    // epilogue: exp, store, rowsum
    size_t hbb = (size_t)h * B * B;
    int colbase = kt * 128 + wc * 64 + (l & 15);
#pragma unroll
    for (int i = 0; i < 4; ++i) {
        float rs[4] = {0.f, 0.f, 0.f, 0.f};
        int qrow0 = qt * 128 + wr * 64 + i * 16 + (l >> 4) * 4;
#pragma unroll
        for (int j = 0; j < 4; ++j) {
#pragma unroll
            for (int reg = 0; reg < 4; ++reg) {
                float e = __expf(acc[i][j][reg] * 0.125f);
                attn[hbb + (size_t)(qrow0 + reg) * B + colbase + j * 16] = e;
                rs[reg] += e;
            }
        }
#pragma unroll
        for (int reg = 0; reg < 4; ++reg) {
            float s = rs[reg];
            s += __shfl_xor(s, 1); s += __shfl_xor(s, 2);
            s += __shfl_xor(s, 4); s += __shfl_xor(s, 8);
            if ((l & 15) == 0) atomicAdd(&rowsum[h * B + qrow0 + reg], s);
        }
    }
}

// ---------------------------------------------------------------------------
// K3 (fused): attn = E/rowsum (write back), colsum += attn,
//             ovp[ct] = P_chunk @ V_chunk (full PV, unmasked, split-K by ct)
// ---------------------------------------------------------------------------
__global__ __launch_bounds__(256) void norm_colsum_pv(float* __restrict__ attn,
                                                      const float* __restrict__ qkv,
                                                      const float* __restrict__ rowsum,
                                                      float* __restrict__ colsum,
                                                      float* __restrict__ ovp) {
    int ct = blockIdx.x;   // 0..3
    int rt = blockIdx.y;   // 0..31
    int h = blockIdx.z;
    int tid = threadIdx.x;
    int lane = tid & 63;
    __shared__ float As[32][68];
    __shared__ float Bs[32][68];
    __shared__ float cs[512];
    __shared__ float rinv_s[64];
    if (tid < 64) rinv_s[tid] = 1.0f / rowsum[h * B + rt * 64 + tid];
    for (int i = tid; i < 512; i += 256) cs[i] = 0.f;
    __syncthreads();

    int tx = tid % 16, ty = tid / 16;
    int r = tid / 8;
    int c4 = (tid % 8) * 4;
    float acc[4][4] = {};
    size_t abase = (size_t)h * B * B + (size_t)(rt * 64) * B + ct * 512;
    const float* vbase = qkv + 1024 + h * 64;

    for (int s = 0; s < 16; ++s) {
        float cp[4] = {0.f, 0.f, 0.f, 0.f};
#pragma unroll
        for (int p = 0; p < 2; ++p) {
            int rr = p * 32 + r;
            float rv = rinv_s[rr];
            size_t idx = abase + (size_t)rr * B + s * 32 + c4;
            float4 v = *(const float4*)(attn + idx);
            v.x *= rv; v.y *= rv; v.z *= rv; v.w *= rv;
            *(float4*)(attn + idx) = v;
            As[c4 + 0][rr] = v.x; As[c4 + 1][rr] = v.y;
            As[c4 + 2][rr] = v.z; As[c4 + 3][rr] = v.w;
            cp[0] += v.x; cp[1] += v.y; cp[2] += v.z; cp[3] += v.w;
        }
        {
            int br = tid / 16;
            int bc4 = (tid % 16) * 4;
#pragma unroll
            for (int p = 0; p < 2; ++p) {
                int rr = p * 16 + br;
                *(float4*)&Bs[rr][bc4] =
                    *(const float4*)(vbase + (size_t)(ct * 512 + s * 32 + rr) * QKVN + bc4);
            }
        }
#pragma unroll
        for (int j = 0; j < 4; ++j) {
            cp[j] += __shfl_xor(cp[j], 8);
            cp[j] += __shfl_xor(cp[j], 16);
            cp[j] += __shfl_xor(cp[j], 32);
        }
        if (lane < 8) {
#pragma unroll
            for (int j = 0; j < 4; ++j) atomicAdd(&cs[s * 32 + c4 + j], cp[j]);
        }
        __syncthreads();
#pragma unroll 8
        for (int kk = 0; kk < 32; ++kk) {
            float4 av = *(const float4*)&As[kk][ty * 4];
            float4 bv = *(const float4*)&Bs[kk][tx * 4];
            const float* ap = &av.x;
            const float* bp = &bv.x;
#pragma unroll
            for (int i = 0; i < 4; ++i)
#pragma unroll
                for (int j = 0; j < 4; ++j) acc[i][j] += ap[i] * bp[j];
        }
        __syncthreads();
    }
    for (int i = tid; i < 512; i += 256)
        atomicAdd(&colsum[h * B + ct * 512 + i], cs[i]);
#pragma unroll
    for (int i = 0; i < 4; ++i) {
        float4 c = make_float4(acc[i][0], acc[i][1], acc[i][2], acc[i][3]);
        *(float4*)(ovp + ((size_t)ct * B + rt * 64 + ty * 4 + i) * DIM + h * 64 + tx * 4) = c;
    }
}

// ---------------------------------------------------------------------------
// K4: top-5 columns per head by colsum
// ---------------------------------------------------------------------------
__global__ __launch_bounds__(256) void topk5(const float* __restrict__ colsum,
                                             int* __restrict__ topidx) {
    int h = blockIdx.x;
    __shared__ float v[B];
    __shared__ float bv[256];
    __shared__ int bi[256];
    int tid = threadIdx.x;
    for (int i = tid; i < B; i += 256) v[i] = colsum[h * B + i];
    __syncthreads();
    for (int it = 0; it < 5; ++it) {
        float best = -1e30f;
        int bidx = 0;
        for (int i = tid; i < B; i += 256) {
            float x = v[i];
            if (x > best || (x == best && i < bidx)) { best = x; bidx = i; }
        }
        bv[tid] = best; bi[tid] = bidx;
        __syncthreads();
        for (int s = 128; s > 0; s >>= 1) {
            if (tid < s) {
                if (bv[tid + s] > bv[tid] ||
                    (bv[tid + s] == bv[tid] && bi[tid + s] < bi[tid])) {
                    bv[tid] = bv[tid + s]; bi[tid] = bi[tid + s];
                }
            }
            __syncthreads();
        }
        if (tid == 0) { topidx[h * 8 + it] = bi[0]; v[bi[0]] = -1e30f; }
        __syncthreads();
    }
}

// ---------------------------------------------------------------------------
// K5: maskfix — reduce ovp partials, subtract top-5 column correction,
//     zero the masked attn columns.
// ---------------------------------------------------------------------------
__global__ __launch_bounds__(256) void maskfix(float* __restrict__ attn,
                                               const float* __restrict__ qkv,
                                               const int* __restrict__ topidx,
                                               const float* __restrict__ ovp,
                                               float* __restrict__ ov) {
    int rt = blockIdx.x;
    int h = blockIdx.y;
    int tid = threadIdx.x;
    __shared__ float Pl[5][64];
    __shared__ float Vl[5][64];
    __shared__ int tix[5];
    if (tid < 5) tix[tid] = topidx[h * 8 + tid];
    __syncthreads();
    size_t abase = (size_t)h * B * B + (size_t)(rt * 64) * B;
    for (int t = tid; t < 320; t += 256) {
        int i = t / 64, q = t % 64;
        Pl[i][q] = attn[abase + (size_t)q * B + tix[i]];
        Vl[i][q] = qkv[(size_t)tix[i] * QKVN + 1024 + h * 64 + q];
    }
    __syncthreads();
    for (int t = tid; t < 320; t += 256) {
        int i = t / 64, q = t % 64;
        attn[abase + (size_t)q * B + tix[i]] = 0.f;
    }
    int tx = tid % 16, ty = tid / 16;
    float corr[4][4] = {};
#pragma unroll
    for (int i = 0; i < 5; ++i)
#pragma unroll
        for (int a = 0; a < 4; ++a)
#pragma unroll
            for (int b2 = 0; b2 < 4; ++b2)
                corr[a][b2] += Pl[i][ty * 4 + a] * Vl[i][tx * 4 + b2];
#pragma unroll
    for (int a = 0; a < 4; ++a) {
        size_t row = (size_t)(rt * 64 + ty * 4 + a);
        size_t col = h * 64 + tx * 4;
        float4 s0 = *(const float4*)(ovp + ((size_t)0 * B + row) * DIM + col);
        float4 s1 = *(const float4*)(ovp + ((size_t)1 * B + row) * DIM + col);
        float4 s2 = *(const float4*)(ovp + ((size_t)2 * B + row) * DIM + col);
        float4 s3 = *(const float4*)(ovp + ((size_t)3 * B + row) * DIM + col);
        float4 o;
        o.x = s0.x + s1.x + s2.x + s3.x - corr[a][0];
        o.y = s0.y + s1.y + s2.y + s3.y - corr[a][1];
        o.z = s0.z + s1.z + s2.z + s3.z - corr[a][2];
        o.w = s0.w + s1.w + s2.w + s3.w - corr[a][3];
        *(float4*)(ov + row * DIM + col) = o;
    }
}

// ---------------------------------------------------------------------------
// K7: y = ov @ W_proj^T + b_proj
// ---------------------------------------------------------------------------
__global__ __launch_bounds__(256) void proj_gemm(const float* __restrict__ ov,
                                                 const float* __restrict__ wproj,
                                                 const float* __restrict__ bproj,
                                                 float* __restrict__ y) {
    int nt = blockIdx.x;
    int mt = blockIdx.y;
    __shared__ float As[32][68];
    __shared__ float Bs[32][68];
    int tid = threadIdx.x;
    int tx = tid % 16, ty = tid / 16;
    float acc[4][4] = {};
    for (int k0 = 0; k0 < 512; k0 += 32) {
        {
            int r = tid / 8;
            int c4 = (tid % 8) * 4;
#pragma unroll
            for (int p = 0; p < 2; ++p) {
                int rr = p * 32 + r;
                float4 a = *(const float4*)(ov + (size_t)(mt * 64 + rr) * DIM + k0 + c4);
                As[c4 + 0][rr] = a.x; As[c4 + 1][rr] = a.y;
                As[c4 + 2][rr] = a.z; As[c4 + 3][rr] = a.w;
                float4 b = *(const float4*)(wproj + (size_t)(nt * 64 + rr) * DIM + k0 + c4);
                Bs[c4 + 0][rr] = b.x; Bs[c4 + 1][rr] = b.y;
                Bs[c4 + 2][rr] = b.z; Bs[c4 + 3][rr] = b.w;
            }
        }
        __syncthreads();
#pragma unroll 8
        for (int kk = 0; kk < 32; ++kk) {
            float4 av = *(const float4*)&As[kk][ty * 4];
            float4 bv = *(const float4*)&Bs[kk][tx * 4];
            const float* ap = &av.x;
            const float* bp = &bv.x;
#pragma unroll
            for (int i = 0; i < 4; ++i)
#pragma unroll
                for (int j = 0; j < 4; ++j) acc[i][j] += ap[i] * bp[j];
        }
        __syncthreads();
    }
#pragma unroll
    for (int i = 0; i < 4; ++i) {
        float4 c;
        c.x = acc[i][0] + bproj[nt * 64 + tx * 4 + 0];
        c.y = acc[i][1] + bproj[nt * 64 + tx * 4 + 1];
        c.z = acc[i][2] + bproj[nt * 64 + tx * 4 + 2];
        c.w = acc[i][3] + bproj[nt * 64 + tx * 4 + 3];
        *(float4*)(y + (size_t)(mt * 64 + ty * 4 + i) * DIM + nt * 64 + tx * 4) = c;
    }
}

// ---------------------------------------------------------------------------
// K8a: BN partial sums (64 blocks x 32 rows each), atomics into sums/ssums
// ---------------------------------------------------------------------------
__global__ __launch_bounds__(256) void bn_partial(const float* __restrict__ y,
                                                  float* __restrict__ sums,
                                                  float* __restrict__ ssums) {
    int r0 = blockIdx.x * 32;
    int tid = threadIdx.x;
    int c2 = tid * 2;
    float s0 = 0.f, s1 = 0.f, q0 = 0.f, q1 = 0.f;
    for (int r = 0; r < 32; ++r) {
        float2 v = *(const float2*)(y + (size_t)(r0 + r) * DIM + c2);
        s0 += v.x; s1 += v.y;
        q0 += v.x * v.x; q1 += v.y * v.y;
    }
    atomicAdd(&sums[c2 + 0], s0);
    atomicAdd(&sums[c2 + 1], s1);
    atomicAdd(&ssums[c2 + 0], q0);
    atomicAdd(&ssums[c2 + 1], q1);
}

// K8b: finalize mean/rstd
__global__ __launch_bounds__(512) void bn_finalize(const float* __restrict__ sums,
                                                   const float* __restrict__ ssums,
                                                   float* __restrict__ mean_out,
                                                   float* __restrict__ rstd_out) {
    int c = threadIdx.x;
    float m = sums[c] * (1.0f / B);
    float var = ssums[c] * (1.0f / B) - m * m;
    mean_out[c] = m;
    rstd_out[c] = rsqrtf(var + 1e-5f);
}

// ---------------------------------------------------------------------------
// K9: out = relu(gamma*(y-mean)*rstd + beta)
// ---------------------------------------------------------------------------
__global__ __launch_bounds__(256) void bn_apply(const float* __restrict__ y,
                                                const float* __restrict__ mean,
                                                const float* __restrict__ rstd,
                                                const float* __restrict__ gamma,
                                                const float* __restrict__ beta,
                                                float* __restrict__ out) {
    int t = blockIdx.x * 256 + threadIdx.x;
    int c4 = (t % 128) * 4;
    size_t r = t / 128;
    if (r >= B) return;
    float4 v = *(const float4*)(y + r * DIM + c4);
    float4 m = *(const float4*)(mean + c4);
    float4 rs = *(const float4*)(rstd + c4);
    float4 g = *(const float4*)(gamma + c4);
    float4 bt = *(const float4*)(beta + c4);
    float4 o;
    o.x = fmaxf(0.f, g.x * (v.x - m.x) * rs.x + bt.x);
    o.y = fmaxf(0.f, g.y * (v.y - m.y) * rs.y + bt.y);
    o.z = fmaxf(0.f, g.z * (v.z - m.z) * rs.z + bt.z);
    o.w = fmaxf(0.f, g.w * (v.w - m.w) * rs.w + bt.w);
    *(float4*)(out + r * DIM + c4) = o;
}

// ---------------------------------------------------------------------------
extern "C" void kernel_launch(void* const* d_in, const int* in_sizes, int n_in,
                              void* d_out, int out_size, void* d_ws, size_t ws_size,
                              hipStream_t stream) {
    const float* x = (const float*)d_in[0];
    const float* W_qkv = (const float*)d_in[1];
    const float* W_proj = (const float*)d_in[2];
    const float* b_proj = (const float*)d_in[3];
    const float* bn_gamma = (const float*)d_in[4];
    const float* bn_beta = (const float*)d_in[5];

    float* out0 = (float*)d_out;                         // [2048,512]
    float* attn = (float*)d_out + OUT0_ELEMS;            // [8,2048,2048]

    float* ws = (float*)d_ws;
    float* qkv = ws;                                     // 3,145,728
    float* ovp = qkv + (size_t)B * QKVN;                 // 4 * 1,048,576
    float* ov = ovp + 4 * OUT0_ELEMS;                    // 1,048,576
    float* y = ov + OUT0_ELEMS;                          // 1,048,576
    float* rowsum = y + OUT0_ELEMS;                      // 16,384
    float* colsum = rowsum + NH * B;                     // 16,384
    float* bn_mean = colsum + NH * B;                    // 512
    float* bn_rstd = bn_mean + DIM;                      // 512
    int* topidx = (int*)(bn_rstd + DIM);                 // 64 ints
    float* sums = (float*)(topidx + 64);                 // 512
    float* ssums = sums + DIM;                           // 512
    // qkbf (4 MB of bf16 q,k) aliases ovp: written by gemm_qkv, consumed by
    // logits_mfma, both strictly before norm_colsum_pv writes ovp.
    unsigned short* qkbf = (unsigned short*)ovp;

    hipMemsetAsync(rowsum, 0, 2 * NH * B * sizeof(float), stream);   // rowsum+colsum
    hipMemsetAsync(sums, 0, 2 * DIM * sizeof(float), stream);        // sums+ssums

    gemm_qkv<<<dim3(QKVN / 64, B / 64), 256, 0, stream>>>(x, W_qkv, qkv, qkbf);
    logits_mfma<<<dim3(B / 128, B / 128, NH), 256, 0, stream>>>(qkbf, attn, rowsum);
    norm_colsum_pv<<<dim3(4, B / 64, NH), 256, 0, stream>>>(attn, qkv, rowsum, colsum, ovp);
    topk5<<<NH, 256, 0, stream>>>(colsum, topidx);
    maskfix<<<dim3(B / 64, NH), 256, 0, stream>>>(attn, qkv, topidx, ovp, ov);
    proj_gemm<<<dim3(DIM / 64, B / 64), 256, 0, stream>>>(ov, W_proj, b_proj, y);
    bn_partial<<<B / 32, 256, 0, stream>>>(y, sums, ssums);
    bn_finalize<<<1, 512, 0, stream>>>(sums, ssums, bn_mean, bn_rstd);
    bn_apply<<<(B * DIM / 4 + 255) / 256, 256, 0, stream>>>(y, bn_mean, bn_rstd,
                                                            bn_gamma, bn_beta, out0);
}

// Round 5
// 175.014 us; speedup vs baseline: 2.9047x; 1.3752x over previous
//
#include <hip/hip_runtime.h>
#include <hip/hip_bf16.h>

#define B 2048
#define NH 8
#define HD 64
#define DIM 512
#define QKVN 1536
#define OUT0_ELEMS ((size_t)B * DIM)        // 1,048,576

typedef float f32x4 __attribute__((ext_vector_type(4)));
typedef __bf16 bf16x8 __attribute__((ext_vector_type(8)));

static __device__ __forceinline__ unsigned short f2bf(float f) {
    unsigned int u = __builtin_bit_cast(unsigned int, f);
    u += 0x7fffu + ((u >> 16) & 1u);   // RNE (values are tame, no NaN path)
    return (unsigned short)(u >> 16);
}

// ---------------------------------------------------------------------------
// K1: qkv GEMM. Writes bf16 copy of ALL of qkv (q,k,v) and fp32 copy of v only.
// ---------------------------------------------------------------------------
__global__ __launch_bounds__(256) void gemm_qkv(const float* __restrict__ x,
                                                const float* __restrict__ w,
                                                float* __restrict__ v_f32,
                                                unsigned short* __restrict__ qkvbf) {
    int nt = blockIdx.x;   // 0..23
    int mt = blockIdx.y;   // 0..31
    __shared__ float As[32][68];
    __shared__ float Bs[32][68];
    int tid = threadIdx.x;
    int tx = tid % 16, ty = tid / 16;
    float acc[4][4] = {};
    for (int k0 = 0; k0 < 512; k0 += 32) {
        {
            int r = tid / 8;
            int c4 = (tid % 8) * 4;
#pragma unroll
            for (int p = 0; p < 2; ++p) {
                int rr = p * 32 + r;
                float4 a = *(const float4*)(x + (size_t)(mt * 64 + rr) * 512 + k0 + c4);
                As[c4 + 0][rr] = a.x; As[c4 + 1][rr] = a.y;
                As[c4 + 2][rr] = a.z; As[c4 + 3][rr] = a.w;
            }
            int br = tid / 16;
            int bc4 = (tid % 16) * 4;
#pragma unroll
            for (int p = 0; p < 2; ++p) {
                int rr = p * 16 + br;
                *(float4*)&Bs[rr][bc4] = *(const float4*)(w + (size_t)(k0 + rr) * QKVN + nt * 64 + bc4);
            }
        }
        __syncthreads();
#pragma unroll 8
        for (int kk = 0; kk < 32; ++kk) {
            float4 av = *(const float4*)&As[kk][ty * 4];
            float4 bv = *(const float4*)&Bs[kk][tx * 4];
            const float* ap = &av.x;
            const float* bp = &bv.x;
#pragma unroll
            for (int i = 0; i < 4; ++i)
#pragma unroll
                for (int j = 0; j < 4; ++j) acc[i][j] += ap[i] * bp[j];
        }
        __syncthreads();
    }
#pragma unroll
    for (int i = 0; i < 4; ++i) {
        float4 c = make_float4(acc[i][0], acc[i][1], acc[i][2], acc[i][3]);
        size_t row = (size_t)(mt * 64 + ty * 4 + i);
        ushort4 u;
        u.x = f2bf(c.x); u.y = f2bf(c.y); u.z = f2bf(c.z); u.w = f2bf(c.w);
        *(ushort4*)(qkvbf + row * QKVN + nt * 64 + tx * 4) = u;
        if (nt >= 16)   // v columns, fp32 compact copy for maskfix correction
            *(float4*)(v_f32 + row * DIM + (nt - 16) * 64 + tx * 4) = c;
    }
}

// ---------------------------------------------------------------------------
// K2: transpose V (bf16) to vT[h][d][k] so PV B-fragments are k-contiguous
// ---------------------------------------------------------------------------
__global__ __launch_bounds__(256) void v_transpose(const unsigned short* __restrict__ qkvbf,
                                                   unsigned short* __restrict__ vT) {
    int kt = blockIdx.x;   // 0..15 (128 k rows)
    int h = blockIdx.y;
    __shared__ unsigned short T[64][136];
    int tid = threadIdx.x;
    const uint4* src = (const uint4*)qkvbf;
#pragma unroll
    for (int p = 0; p < 4; ++p) {            // FIX: 1024 uint4 (was 512)
        int chunk = p * 256 + tid;
        int k = chunk >> 3, c = chunk & 7;   // FIX: c = 8-d group in [0,8)
        uint4 v = src[(size_t)(kt * 128 + k) * 192 + 128 + h * 8 + c];
        T[c * 8 + 0][k] = (unsigned short)(v.x & 0xffff);
        T[c * 8 + 1][k] = (unsigned short)(v.x >> 16);
        T[c * 8 + 2][k] = (unsigned short)(v.y & 0xffff);
        T[c * 8 + 3][k] = (unsigned short)(v.y >> 16);
        T[c * 8 + 4][k] = (unsigned short)(v.z & 0xffff);
        T[c * 8 + 5][k] = (unsigned short)(v.z >> 16);
        T[c * 8 + 6][k] = (unsigned short)(v.w & 0xffff);
        T[c * 8 + 7][k] = (unsigned short)(v.w >> 16);
    }
    __syncthreads();
#pragma unroll
    for (int p = 0; p < 4; ++p) {
        int chunk = p * 256 + tid;
        int d = chunk >> 4, kc = chunk & 15;
        const unsigned short* tr = &T[d][kc * 8];
        uint4 o;
        o.x = (unsigned)tr[0] | ((unsigned)tr[1] << 16);
        o.y = (unsigned)tr[2] | ((unsigned)tr[3] << 16);
        o.z = (unsigned)tr[4] | ((unsigned)tr[5] << 16);
        o.w = (unsigned)tr[6] | ((unsigned)tr[7] << 16);
        *(uint4*)(vT + ((size_t)(h * 64 + d) * 2048 + kt * 128 + kc * 8)) = o;
    }
}

// ---------------------------------------------------------------------------
// K3: the attention pass. PHASE 1: rowsums only (no attn write).
//     PHASE 2: recompute QK^T, normalize, write P fp32, colsum, PV via MFMA.
// grid (ct=4 k-chunks of 512, qt=16 q-tiles of 128, h=8), 256 thr (4 waves 2x2)
// ---------------------------------------------------------------------------
template<int PHASE>
__global__ __launch_bounds__(256) void attn_pass(const unsigned short* __restrict__ qkvbf,
                                                 const unsigned short* __restrict__ vT,
                                                 const float* __restrict__ rowsum_in,
                                                 float* __restrict__ rowsum_out,
                                                 float* __restrict__ attn,
                                                 float* __restrict__ colsum,
                                                 float* __restrict__ ovp) {
    int ct = blockIdx.x, qt = blockIdx.y, h = blockIdx.z;
    int tid = threadIdx.x;
    int l = tid & 63;
    int wid = tid >> 6;
    int wr = wid >> 1;   // q half (64)
    int wc = wid & 1;    // k/d half (32 within 64)

    __shared__ uint4 Qs[128 * 8];
    __shared__ uint4 Ks[64 * 8];
    __shared__ uint4 Vt[64 * 8];
    __shared__ uint4 Pl4[128 * 8];
    __shared__ float cs[512];
    __shared__ float rinv[128];
    unsigned short* Pl = (unsigned short*)Pl4;

    const uint4* src = (const uint4*)qkvbf;   // row = 192 uint4
    // stage Q tile (128 rows x 8 slots), granule-swizzled
#pragma unroll
    for (int it = 0; it < 4; ++it) {
        int chunk = it * 256 + tid;
        int row = chunk >> 3, slot = chunk & 7;
        Qs[row * 8 + (slot ^ (row & 7))] = src[(size_t)(qt * 128 + row) * 192 + h * 8 + slot];
    }
    if constexpr (PHASE == 2) {
        if (tid < 128) rinv[tid] = 1.0f / rowsum_in[h * B + qt * 128 + tid];
        if (tid < 256) { cs[tid] = 0.f; cs[tid + 256] = 0.f; }
    }

    float rsum[4][4];
    f32x4 O[4][2];
    if constexpr (PHASE == 1) {
#pragma unroll
        for (int i = 0; i < 4; ++i)
#pragma unroll
            for (int r = 0; r < 4; ++r) rsum[i][r] = 0.f;
    } else {
#pragma unroll
        for (int i = 0; i < 4; ++i)
#pragma unroll
            for (int j = 0; j < 2; ++j) O[i][j] = (f32x4){0.f, 0.f, 0.f, 0.f};
    }

    size_t hbb = (size_t)h * B * B;
    for (int sub = 0; sub < 8; ++sub) {
        int kbase = ct * 512 + sub * 64;
        // stage K subtile (64 rows x 8 slots)
#pragma unroll
        for (int it = 0; it < 2; ++it) {
            int chunk = it * 256 + tid;
            int row = chunk >> 3, slot = chunk & 7;
            Ks[row * 8 + (slot ^ (row & 7))] = src[(size_t)(kbase + row) * 192 + 64 + h * 8 + slot];
        }
        if constexpr (PHASE == 2) {
            // stage V^T subtile: Vt[d][k-granules], swizzled
#pragma unroll
            for (int it = 0; it < 2; ++it) {
                int chunk = it * 256 + tid;
                int d = chunk >> 3, g = chunk & 7;
                Vt[d * 8 + (g ^ (d & 7))] =
                    *(const uint4*)(vT + ((size_t)(h * 64 + d) * 2048 + kbase + g * 8));
            }
        }
        __syncthreads();

        // ---- QK^T ----
        f32x4 S[4][2];
#pragma unroll
        for (int i = 0; i < 4; ++i)
#pragma unroll
            for (int j = 0; j < 2; ++j) S[i][j] = (f32x4){0.f, 0.f, 0.f, 0.f};
#pragma unroll
        for (int km = 0; km < 2; ++km) {
            int gsel = km * 4 + (l >> 4);
            bf16x8 aq[4], bk[2];
#pragma unroll
            for (int i = 0; i < 4; ++i) {
                int row = wr * 64 + i * 16 + (l & 15);
                aq[i] = __builtin_bit_cast(bf16x8, Qs[row * 8 + (gsel ^ (row & 7))]);
            }
#pragma unroll
            for (int j = 0; j < 2; ++j) {
                int row = wc * 32 + j * 16 + (l & 15);
                bk[j] = __builtin_bit_cast(bf16x8, Ks[row * 8 + (gsel ^ (row & 7))]);
            }
#pragma unroll
            for (int i = 0; i < 4; ++i)
#pragma unroll
                for (int j = 0; j < 2; ++j)
                    S[i][j] = __builtin_amdgcn_mfma_f32_16x16x32_bf16(aq[i], bk[j], S[i][j], 0, 0, 0);
        }

        if constexpr (PHASE == 1) {
#pragma unroll
            for (int i = 0; i < 4; ++i)
#pragma unroll
                for (int j = 0; j < 2; ++j)
#pragma unroll
                    for (int reg = 0; reg < 4; ++reg)
                        rsum[i][reg] += __expf(S[i][j][reg] * 0.125f);
            __syncthreads();   // protect Ks before restage
        } else {
            // ---- P = exp*rinv; write attn fp32; colsum; stash bf16 in Pl ----
            float csacc[2] = {0.f, 0.f};
#pragma unroll
            for (int i = 0; i < 4; ++i) {
#pragma unroll
                for (int j = 0; j < 2; ++j) {
                    int kcol = wc * 32 + j * 16 + (l & 15);
#pragma unroll
                    for (int reg = 0; reg < 4; ++reg) {
                        int qrow = wr * 64 + i * 16 + (l >> 4) * 4 + reg;
                        float p = __expf(S[i][j][reg] * 0.125f) * rinv[qrow];
                        attn[hbb + (size_t)(qt * 128 + qrow) * B + kbase + kcol] = p;
                        csacc[j] += p;
                        Pl[qrow * 64 + ((kcol & 7) | ((((kcol >> 3) ^ (qrow & 7))) << 3))] = f2bf(p);
                    }
                }
            }
#pragma unroll
            for (int j = 0; j < 2; ++j) {
                float v = csacc[j];
                v += __shfl_xor(v, 16);
                v += __shfl_xor(v, 32);
                if (l < 16) atomicAdd(&cs[sub * 64 + wc * 32 + j * 16 + l], v);
            }
            __syncthreads();   // Pl visible to all waves
            // ---- PV: O += P(128x64) @ V(64x64) ----
#pragma unroll
            for (int km = 0; km < 2; ++km) {
                int gsel = km * 4 + (l >> 4);
                bf16x8 pa[4], vb[2];
#pragma unroll
                for (int i = 0; i < 4; ++i) {
                    int q = wr * 64 + i * 16 + (l & 15);
                    pa[i] = __builtin_bit_cast(bf16x8, Pl4[q * 8 + (gsel ^ (q & 7))]);
                }
#pragma unroll
                for (int j = 0; j < 2; ++j) {
                    int d = wc * 32 + j * 16 + (l & 15);
                    vb[j] = __builtin_bit_cast(bf16x8, Vt[d * 8 + (gsel ^ (d & 7))]);
                }
#pragma unroll
                for (int i = 0; i < 4; ++i)
#pragma unroll
                    for (int j = 0; j < 2; ++j)
                        O[i][j] = __builtin_amdgcn_mfma_f32_16x16x32_bf16(pa[i], vb[j], O[i][j], 0, 0, 0);
            }
            __syncthreads();   // protect Ks/Vt/Pl before restage
        }
    }

    if constexpr (PHASE == 1) {
#pragma unroll
        for (int i = 0; i < 4; ++i)
#pragma unroll
            for (int reg = 0; reg < 4; ++reg) {
                float v = rsum[i][reg];
                v += __shfl_xor(v, 1); v += __shfl_xor(v, 2);
                v += __shfl_xor(v, 4); v += __shfl_xor(v, 8);
                if ((l & 15) == 0)
                    atomicAdd(&rowsum_out[h * B + qt * 128 + wr * 64 + i * 16 + (l >> 4) * 4 + reg], v);
            }
    } else {
        for (int i = tid; i < 512; i += 256)
            atomicAdd(&colsum[h * B + ct * 512 + i], cs[i]);
#pragma unroll
        for (int i = 0; i < 4; ++i)
#pragma unroll
            for (int j = 0; j < 2; ++j)
#pragma unroll
                for (int reg = 0; reg < 4; ++reg) {
                    int qrow = wr * 64 + i * 16 + (l >> 4) * 4 + reg;
                    ovp[((size_t)ct * B + qt * 128 + qrow) * DIM + h * 64 + wc * 32 + j * 16 + (l & 15)] =
                        O[i][j][reg];
                }
    }
}

// ---------------------------------------------------------------------------
// K4: top-5 columns per head by colsum
// ---------------------------------------------------------------------------
__global__ __launch_bounds__(256) void topk5(const float* __restrict__ colsum,
                                             int* __restrict__ topidx) {
    int h = blockIdx.x;
    __shared__ float v[B];
    __shared__ float bv[256];
    __shared__ int bi[256];
    int tid = threadIdx.x;
    for (int i = tid; i < B; i += 256) v[i] = colsum[h * B + i];
    __syncthreads();
    for (int it = 0; it < 5; ++it) {
        float best = -1e30f;
        int bidx = 0;
        for (int i = tid; i < B; i += 256) {
            float x = v[i];
            if (x > best || (x == best && i < bidx)) { best = x; bidx = i; }
        }
        bv[tid] = best; bi[tid] = bidx;
        __syncthreads();
        for (int s = 128; s > 0; s >>= 1) {
            if (tid < s) {
                if (bv[tid + s] > bv[tid] ||
                    (bv[tid + s] == bv[tid] && bi[tid + s] < bi[tid])) {
                    bv[tid] = bv[tid + s]; bi[tid] = bi[tid + s];
                }
            }
            __syncthreads();
        }
        if (tid == 0) { topidx[h * 8 + it] = bi[0]; v[bi[0]] = -1e30f; }
        __syncthreads();
    }
}

// ---------------------------------------------------------------------------
// K5: maskfix — reduce ovp partials, subtract top-5 column correction (fp32),
//     zero the masked attn columns.
// ---------------------------------------------------------------------------
__global__ __launch_bounds__(256) void maskfix(float* __restrict__ attn,
                                               const float* __restrict__ v_f32,
                                               const int* __restrict__ topidx,
                                               const float* __restrict__ ovp,
                                               float* __restrict__ ov) {
    int rt = blockIdx.x;
    int h = blockIdx.y;
    int tid = threadIdx.x;
    __shared__ float Pl[5][64];
    __shared__ float Vl[5][64];
    __shared__ int tix[5];
    if (tid < 5) tix[tid] = topidx[h * 8 + tid];
    __syncthreads();
    size_t abase = (size_t)h * B * B + (size_t)(rt * 64) * B;
    for (int t = tid; t < 320; t += 256) {
        int i = t / 64, q = t % 64;
        Pl[i][q] = attn[abase + (size_t)q * B + tix[i]];
        Vl[i][q] = v_f32[(size_t)tix[i] * DIM + h * 64 + q];
    }
    __syncthreads();
    for (int t = tid; t < 320; t += 256) {
        int i = t / 64, q = t % 64;
        attn[abase + (size_t)q * B + tix[i]] = 0.f;
    }
    int tx = tid % 16, ty = tid / 16;
    float corr[4][4] = {};
#pragma unroll
    for (int i = 0; i < 5; ++i)
#pragma unroll
        for (int a = 0; a < 4; ++a)
#pragma unroll
            for (int b2 = 0; b2 < 4; ++b2)
                corr[a][b2] += Pl[i][ty * 4 + a] * Vl[i][tx * 4 + b2];
#pragma unroll
    for (int a = 0; a < 4; ++a) {
        size_t row = (size_t)(rt * 64 + ty * 4 + a);
        size_t col = h * 64 + tx * 4;
        float4 s0 = *(const float4*)(ovp + ((size_t)0 * B + row) * DIM + col);
        float4 s1 = *(const float4*)(ovp + ((size_t)1 * B + row) * DIM + col);
        float4 s2 = *(const float4*)(ovp + ((size_t)2 * B + row) * DIM + col);
        float4 s3 = *(const float4*)(ovp + ((size_t)3 * B + row) * DIM + col);
        float4 o;
        o.x = s0.x + s1.x + s2.x + s3.x - corr[a][0];
        o.y = s0.y + s1.y + s2.y + s3.y - corr[a][1];
        o.z = s0.z + s1.z + s2.z + s3.z - corr[a][2];
        o.w = s0.w + s1.w + s2.w + s3.w - corr[a][3];
        *(float4*)(ov + row * DIM + col) = o;
    }
}

// ---------------------------------------------------------------------------
// K7: y = ov @ W_proj^T + b_proj
// ---------------------------------------------------------------------------
__global__ __launch_bounds__(256) void proj_gemm(const float* __restrict__ ov,
                                                 const float* __restrict__ wproj,
                                                 const float* __restrict__ bproj,
                                                 float* __restrict__ y) {
    int nt = blockIdx.x;
    int mt = blockIdx.y;
    __shared__ float As[32][68];
    __shared__ float Bs[32][68];
    int tid = threadIdx.x;
    int tx = tid % 16, ty = tid / 16;
    float acc[4][4] = {};
    for (int k0 = 0; k0 < 512; k0 += 32) {
        {
            int r = tid / 8;
            int c4 = (tid % 8) * 4;
#pragma unroll
            for (int p = 0; p < 2; ++p) {
                int rr = p * 32 + r;
                float4 a = *(const float4*)(ov + (size_t)(mt * 64 + rr) * DIM + k0 + c4);
                As[c4 + 0][rr] = a.x; As[c4 + 1][rr] = a.y;
                As[c4 + 2][rr] = a.z; As[c4 + 3][rr] = a.w;
                float4 b = *(const float4*)(wproj + (size_t)(nt * 64 + rr) * DIM + k0 + c4);
                Bs[c4 + 0][rr] = b.x; Bs[c4 + 1][rr] = b.y;
                Bs[c4 + 2][rr] = b.z; Bs[c4 + 3][rr] = b.w;
            }
        }
        __syncthreads();
#pragma unroll 8
        for (int kk = 0; kk < 32; ++kk) {
            float4 av = *(const float4*)&As[kk][ty * 4];
            float4 bv = *(const float4*)&Bs[kk][tx * 4];
            const float* ap = &av.x;
            const float* bp = &bv.x;
#pragma unroll
            for (int i = 0; i < 4; ++i)
#pragma unroll
                for (int j = 0; j < 4; ++j) acc[i][j] += ap[i] * bp[j];
        }
        __syncthreads();
    }
#pragma unroll
    for (int i = 0; i < 4; ++i) {
        float4 c;
        c.x = acc[i][0] + bproj[nt * 64 + tx * 4 + 0];
        c.y = acc[i][1] + bproj[nt * 64 + tx * 4 + 1];
        c.z = acc[i][2] + bproj[nt * 64 + tx * 4 + 2];
        c.w = acc[i][3] + bproj[nt * 64 + tx * 4 + 3];
        *(float4*)(y + (size_t)(mt * 64 + ty * 4 + i) * DIM + nt * 64 + tx * 4) = c;
    }
}

// ---------------------------------------------------------------------------
// K8a/K8b: BN stats (2-stage), K9: apply+ReLU
// ---------------------------------------------------------------------------
__global__ __launch_bounds__(256) void bn_partial(const float* __restrict__ y,
                                                  float* __restrict__ sums,
                                                  float* __restrict__ ssums) {
    int r0 = blockIdx.x * 32;
    int tid = threadIdx.x;
    int c2 = tid * 2;
    float s0 = 0.f, s1 = 0.f, q0 = 0.f, q1 = 0.f;
    for (int r = 0; r < 32; ++r) {
        float2 v = *(const float2*)(y + (size_t)(r0 + r) * DIM + c2);
        s0 += v.x; s1 += v.y;
        q0 += v.x * v.x; q1 += v.y * v.y;
    }
    atomicAdd(&sums[c2 + 0], s0);
    atomicAdd(&sums[c2 + 1], s1);
    atomicAdd(&ssums[c2 + 0], q0);
    atomicAdd(&ssums[c2 + 1], q1);
}

__global__ __launch_bounds__(512) void bn_finalize(const float* __restrict__ sums,
                                                   const float* __restrict__ ssums,
                                                   float* __restrict__ mean_out,
                                                   float* __restrict__ rstd_out) {
    int c = threadIdx.x;
    float m = sums[c] * (1.0f / B);
    float var = ssums[c] * (1.0f / B) - m * m;
    mean_out[c] = m;
    rstd_out[c] = rsqrtf(var + 1e-5f);
}

__global__ __launch_bounds__(256) void bn_apply(const float* __restrict__ y,
                                                const float* __restrict__ mean,
                                                const float* __restrict__ rstd,
                                                const float* __restrict__ gamma,
                                                const float* __restrict__ beta,
                                                float* __restrict__ out) {
    int t = blockIdx.x * 256 + threadIdx.x;
    int c4 = (t % 128) * 4;
    size_t r = t / 128;
    if (r >= B) return;
    float4 v = *(const float4*)(y + r * DIM + c4);
    float4 m = *(const float4*)(mean + c4);
    float4 rs = *(const float4*)(rstd + c4);
    float4 g = *(const float4*)(gamma + c4);
    float4 bt = *(const float4*)(beta + c4);
    float4 o;
    o.x = fmaxf(0.f, g.x * (v.x - m.x) * rs.x + bt.x);
    o.y = fmaxf(0.f, g.y * (v.y - m.y) * rs.y + bt.y);
    o.z = fmaxf(0.f, g.z * (v.z - m.z) * rs.z + bt.z);
    o.w = fmaxf(0.f, g.w * (v.w - m.w) * rs.w + bt.w);
    *(float4*)(out + r * DIM + c4) = o;
}

// ---------------------------------------------------------------------------
extern "C" void kernel_launch(void* const* d_in, const int* in_sizes, int n_in,
                              void* d_out, int out_size, void* d_ws, size_t ws_size,
                              hipStream_t stream) {
    const float* x = (const float*)d_in[0];
    const float* W_qkv = (const float*)d_in[1];
    const float* W_proj = (const float*)d_in[2];
    const float* b_proj = (const float*)d_in[3];
    const float* bn_gamma = (const float*)d_in[4];
    const float* bn_beta = (const float*)d_in[5];

    float* out0 = (float*)d_out;                         // [2048,512]
    float* attn = (float*)d_out + OUT0_ELEMS;            // [8,2048,2048]

    float* ws = (float*)d_ws;
    float* v_f32 = ws;                                   // 1,048,576
    float* ovp = v_f32 + OUT0_ELEMS;                     // 4,194,304
    float* ov = ovp + 4 * OUT0_ELEMS;                    // 1,048,576
    float* y = ov + OUT0_ELEMS;                          // 1,048,576
    unsigned short* qkvbf = (unsigned short*)(y + OUT0_ELEMS);   // B*QKVN ushort
    unsigned short* vT = qkvbf + (size_t)B * QKVN;               // NH*HD*B ushort
    float* rowsum = (float*)(vT + (size_t)NH * HD * B);  // 16,384
    float* colsum = rowsum + NH * B;                     // 16,384
    float* bn_mean = colsum + NH * B;                    // 512
    float* bn_rstd = bn_mean + DIM;                      // 512
    int* topidx = (int*)(bn_rstd + DIM);                 // 64 ints
    float* sums = (float*)(topidx + 64);                 // 512
    float* ssums = sums + DIM;                           // 512

    hipMemsetAsync(rowsum, 0, 2 * NH * B * sizeof(float), stream);
    hipMemsetAsync(sums, 0, 2 * DIM * sizeof(float), stream);

    gemm_qkv<<<dim3(QKVN / 64, B / 64), 256, 0, stream>>>(x, W_qkv, v_f32, qkvbf);
    v_transpose<<<dim3(16, NH), 256, 0, stream>>>(qkvbf, vT);
    attn_pass<1><<<dim3(4, 16, NH), 256, 0, stream>>>(qkvbf, vT, nullptr, rowsum,
                                                      attn, colsum, ovp);
    attn_pass<2><<<dim3(4, 16, NH), 256, 0, stream>>>(qkvbf, vT, rowsum, nullptr,
                                                      attn, colsum, ovp);
    topk5<<<NH, 256, 0, stream>>>(colsum, topidx);
    maskfix<<<dim3(B / 64, NH), 256, 0, stream>>>(attn, v_f32, topidx, ovp, ov);
    proj_gemm<<<dim3(DIM / 64, B / 64), 256, 0, stream>>>(ov, W_proj, b_proj, y);
    bn_partial<<<B / 32, 256, 0, stream>>>(y, sums, ssums);
    bn_finalize<<<1, 512, 0, stream>>>(sums, ssums, bn_mean, bn_rstd);
    bn_apply<<<(B * DIM / 4 + 255) / 256, 256, 0, stream>>>(y, bn_mean, bn_rstd,
                                                            bn_gamma, bn_beta, out0);
}

// Round 6
// 144.685 us; speedup vs baseline: 3.5136x; 1.2096x over previous
//
#include <hip/hip_runtime.h>
#include <hip/hip_bf16.h>

#define B 2048
#define NH 8
#define HD 64
#define DIM 512
#define QKVN 1536
#define OUT0_ELEMS ((size_t)B * DIM)        // 1,048,576

typedef float f32x4 __attribute__((ext_vector_type(4)));
typedef __bf16 bf16x8 __attribute__((ext_vector_type(8)));

static __device__ __forceinline__ unsigned short f2bf(float f) {
    unsigned int u = __builtin_bit_cast(unsigned int, f);
    u += 0x7fffu + ((u >> 16) & 1u);   // RNE (values are tame, no NaN path)
    return (unsigned short)(u >> 16);
}
static __device__ __forceinline__ float bfhi2f(unsigned int u) {   // high 16 bits
    return __builtin_bit_cast(float, u & 0xffff0000u);
}
static __device__ __forceinline__ float bflo2f(unsigned int u) {   // low 16 bits
    return __builtin_bit_cast(float, u << 16);
}

// ---------------------------------------------------------------------------
// K0a: cast x to bf16
// ---------------------------------------------------------------------------
__global__ __launch_bounds__(256) void cast_x(const float* __restrict__ x,
                                              unsigned short* __restrict__ xbf) {
    size_t t = (size_t)blockIdx.x * 256 + threadIdx.x;
    float4 v = *(const float4*)(x + t * 4);
    ushort4 u;
    u.x = f2bf(v.x); u.y = f2bf(v.y); u.z = f2bf(v.z); u.w = f2bf(v.w);
    *(ushort4*)(xbf + t * 4) = u;
}

// ---------------------------------------------------------------------------
// K0b: cast + transpose W_qkv [512][1536] -> wT bf16 [1536][512]
// ---------------------------------------------------------------------------
__global__ __launch_bounds__(256) void cast_wT(const float* __restrict__ w,
                                               unsigned short* __restrict__ wT) {
    int n0 = blockIdx.x * 64;   // 0..23
    int k0 = blockIdx.y * 64;   // 0..7
    __shared__ unsigned short T[64][72];   // [n][k]
    int tid = threadIdx.x;
#pragma unroll
    for (int it = 0; it < 4; ++it) {
        int chunk = it * 256 + tid;
        int r = chunk >> 4, c4 = (chunk & 15) * 4;
        float4 v = *(const float4*)(w + (size_t)(k0 + r) * QKVN + n0 + c4);
        T[c4 + 0][r] = f2bf(v.x); T[c4 + 1][r] = f2bf(v.y);
        T[c4 + 2][r] = f2bf(v.z); T[c4 + 3][r] = f2bf(v.w);
    }
    __syncthreads();
#pragma unroll
    for (int it = 0; it < 2; ++it) {
        int chunk = it * 256 + tid;
        int r = chunk >> 3, c8 = (chunk & 7) * 8;
        ushort4 u0, u1;
        u0.x = T[r][c8 + 0]; u0.y = T[r][c8 + 1]; u0.z = T[r][c8 + 2]; u0.w = T[r][c8 + 3];
        u1.x = T[r][c8 + 4]; u1.y = T[r][c8 + 5]; u1.z = T[r][c8 + 6]; u1.w = T[r][c8 + 7];
        *(ushort4*)(wT + (size_t)(n0 + r) * 512 + k0 + c8) = u0;
        *(ushort4*)(wT + (size_t)(n0 + r) * 512 + k0 + c8 + 4) = u1;
    }
}

// ---------------------------------------------------------------------------
// K1: qkv = x @ W_qkv via bf16 MFMA. Tile 128m x 64n, 4 waves (2x2, 64x32 each).
// Writes qkvbf (all) + v_f32 (cols >= 1024).
// ---------------------------------------------------------------------------
__global__ __launch_bounds__(256) void gemm_qkv_mfma(const unsigned short* __restrict__ xbf,
                                                     const unsigned short* __restrict__ wT,
                                                     float* __restrict__ v_f32,
                                                     unsigned short* __restrict__ qkvbf) {
    int nt = blockIdx.x;   // 0..23
    int mt = blockIdx.y;   // 0..15
    __shared__ uint4 Ax[128 * 8];
    __shared__ uint4 Bw[64 * 8];
    int tid = threadIdx.x;
    int l = tid & 63, wid = tid >> 6;
    int wr = wid >> 1, wc = wid & 1;
    const uint4* x4 = (const uint4*)xbf;   // row stride 64 uint4
    const uint4* w4 = (const uint4*)wT;    // row stride 64 uint4
    f32x4 acc[4][2];
#pragma unroll
    for (int i = 0; i < 4; ++i)
#pragma unroll
        for (int j = 0; j < 2; ++j) acc[i][j] = (f32x4){0.f, 0.f, 0.f, 0.f};

    for (int kt = 0; kt < 8; ++kt) {
        int kg = kt * 8;
#pragma unroll
        for (int it = 0; it < 4; ++it) {
            int chunk = it * 256 + tid;
            int row = chunk >> 3, slot = chunk & 7;
            Ax[row * 8 + (slot ^ (row & 7))] = x4[(size_t)(mt * 128 + row) * 64 + kg + slot];
        }
#pragma unroll
        for (int it = 0; it < 2; ++it) {
            int chunk = it * 256 + tid;
            int row = chunk >> 3, slot = chunk & 7;
            Bw[row * 8 + (slot ^ (row & 7))] = w4[(size_t)(nt * 64 + row) * 64 + kg + slot];
        }
        __syncthreads();
#pragma unroll
        for (int km = 0; km < 2; ++km) {
            int gsel = km * 4 + (l >> 4);
            bf16x8 a[4], b[2];
#pragma unroll
            for (int i = 0; i < 4; ++i) {
                int row = wr * 64 + i * 16 + (l & 15);
                a[i] = __builtin_bit_cast(bf16x8, Ax[row * 8 + (gsel ^ (row & 7))]);
            }
#pragma unroll
            for (int j = 0; j < 2; ++j) {
                int row = wc * 32 + j * 16 + (l & 15);
                b[j] = __builtin_bit_cast(bf16x8, Bw[row * 8 + (gsel ^ (row & 7))]);
            }
#pragma unroll
            for (int i = 0; i < 4; ++i)
#pragma unroll
                for (int j = 0; j < 2; ++j)
                    acc[i][j] = __builtin_amdgcn_mfma_f32_16x16x32_bf16(a[i], b[j], acc[i][j], 0, 0, 0);
        }
        __syncthreads();
    }
#pragma unroll
    for (int i = 0; i < 4; ++i)
#pragma unroll
        for (int j = 0; j < 2; ++j)
#pragma unroll
            for (int reg = 0; reg < 4; ++reg) {
                int row = mt * 128 + wr * 64 + i * 16 + (l >> 4) * 4 + reg;
                int col = nt * 64 + wc * 32 + j * 16 + (l & 15);
                float vv = acc[i][j][reg];
                qkvbf[(size_t)row * QKVN + col] = f2bf(vv);
                if (col >= 1024)
                    v_f32[(size_t)row * DIM + col - 1024] = vv;
            }
}

// ---------------------------------------------------------------------------
// K2: transpose V (bf16) to vT[h][d][k]
// ---------------------------------------------------------------------------
__global__ __launch_bounds__(256) void v_transpose(const unsigned short* __restrict__ qkvbf,
                                                   unsigned short* __restrict__ vT) {
    int kt = blockIdx.x;   // 0..15 (128 k rows)
    int h = blockIdx.y;
    __shared__ unsigned short T[64][136];
    int tid = threadIdx.x;
    const uint4* src = (const uint4*)qkvbf;
#pragma unroll
    for (int p = 0; p < 4; ++p) {
        int chunk = p * 256 + tid;
        int k = chunk >> 3, c = chunk & 7;
        uint4 v = src[(size_t)(kt * 128 + k) * 192 + 128 + h * 8 + c];
        T[c * 8 + 0][k] = (unsigned short)(v.x & 0xffff);
        T[c * 8 + 1][k] = (unsigned short)(v.x >> 16);
        T[c * 8 + 2][k] = (unsigned short)(v.y & 0xffff);
        T[c * 8 + 3][k] = (unsigned short)(v.y >> 16);
        T[c * 8 + 4][k] = (unsigned short)(v.z & 0xffff);
        T[c * 8 + 5][k] = (unsigned short)(v.z >> 16);
        T[c * 8 + 6][k] = (unsigned short)(v.w & 0xffff);
        T[c * 8 + 7][k] = (unsigned short)(v.w >> 16);
    }
    __syncthreads();
#pragma unroll
    for (int p = 0; p < 4; ++p) {
        int chunk = p * 256 + tid;
        int d = chunk >> 4, kc = chunk & 15;
        const unsigned short* tr = &T[d][kc * 8];
        uint4 o;
        o.x = (unsigned)tr[0] | ((unsigned)tr[1] << 16);
        o.y = (unsigned)tr[2] | ((unsigned)tr[3] << 16);
        o.z = (unsigned)tr[4] | ((unsigned)tr[5] << 16);
        o.w = (unsigned)tr[6] | ((unsigned)tr[7] << 16);
        *(uint4*)(vT + ((size_t)(h * 64 + d) * 2048 + kt * 128 + kc * 8)) = o;
    }
}

// ---------------------------------------------------------------------------
// K3: attention pass. PHASE 1: rowsums only. PHASE 2: recompute QK^T,
//     normalize, vector-write P (from bf16 LDS stash), colsum, PV via MFMA.
// ---------------------------------------------------------------------------
template<int PHASE>
__global__ __launch_bounds__(256) void attn_pass(const unsigned short* __restrict__ qkvbf,
                                                 const unsigned short* __restrict__ vT,
                                                 const float* __restrict__ rowsum_in,
                                                 float* __restrict__ rowsum_out,
                                                 float* __restrict__ attn,
                                                 float* __restrict__ colsum,
                                                 float* __restrict__ ovp) {
    int ct = blockIdx.x, qt = blockIdx.y, h = blockIdx.z;
    int tid = threadIdx.x;
    int l = tid & 63;
    int wid = tid >> 6;
    int wr = wid >> 1;   // q half (64)
    int wc = wid & 1;    // k/d half (32 within 64)

    __shared__ uint4 Qs[128 * 8];
    __shared__ uint4 Ks[64 * 8];
    __shared__ uint4 Vt[64 * 8];
    __shared__ uint4 Pl4[128 * 8];
    __shared__ float cs[512];
    __shared__ float rinv[128];
    unsigned short* Pl = (unsigned short*)Pl4;

    const uint4* src = (const uint4*)qkvbf;   // row = 192 uint4
#pragma unroll
    for (int it = 0; it < 4; ++it) {
        int chunk = it * 256 + tid;
        int row = chunk >> 3, slot = chunk & 7;
        Qs[row * 8 + (slot ^ (row & 7))] = src[(size_t)(qt * 128 + row) * 192 + h * 8 + slot];
    }
    if constexpr (PHASE == 2) {
        if (tid < 128) rinv[tid] = 1.0f / rowsum_in[h * B + qt * 128 + tid];
        if (tid < 256) { cs[tid] = 0.f; cs[tid + 256] = 0.f; }
    }

    float rsum[4][4];
    f32x4 O[4][2];
    if constexpr (PHASE == 1) {
#pragma unroll
        for (int i = 0; i < 4; ++i)
#pragma unroll
            for (int r = 0; r < 4; ++r) rsum[i][r] = 0.f;
    } else {
#pragma unroll
        for (int i = 0; i < 4; ++i)
#pragma unroll
            for (int j = 0; j < 2; ++j) O[i][j] = (f32x4){0.f, 0.f, 0.f, 0.f};
    }

    size_t hbb = (size_t)h * B * B;
    for (int sub = 0; sub < 8; ++sub) {
        int kbase = ct * 512 + sub * 64;
#pragma unroll
        for (int it = 0; it < 2; ++it) {
            int chunk = it * 256 + tid;
            int row = chunk >> 3, slot = chunk & 7;
            Ks[row * 8 + (slot ^ (row & 7))] = src[(size_t)(kbase + row) * 192 + 64 + h * 8 + slot];
        }
        if constexpr (PHASE == 2) {
#pragma unroll
            for (int it = 0; it < 2; ++it) {
                int chunk = it * 256 + tid;
                int d = chunk >> 3, g = chunk & 7;
                Vt[d * 8 + (g ^ (d & 7))] =
                    *(const uint4*)(vT + ((size_t)(h * 64 + d) * 2048 + kbase + g * 8));
            }
        }
        __syncthreads();

        // ---- QK^T ----
        f32x4 S[4][2];
#pragma unroll
        for (int i = 0; i < 4; ++i)
#pragma unroll
            for (int j = 0; j < 2; ++j) S[i][j] = (f32x4){0.f, 0.f, 0.f, 0.f};
#pragma unroll
        for (int km = 0; km < 2; ++km) {
            int gsel = km * 4 + (l >> 4);
            bf16x8 aq[4], bk[2];
#pragma unroll
            for (int i = 0; i < 4; ++i) {
                int row = wr * 64 + i * 16 + (l & 15);
                aq[i] = __builtin_bit_cast(bf16x8, Qs[row * 8 + (gsel ^ (row & 7))]);
            }
#pragma unroll
            for (int j = 0; j < 2; ++j) {
                int row = wc * 32 + j * 16 + (l & 15);
                bk[j] = __builtin_bit_cast(bf16x8, Ks[row * 8 + (gsel ^ (row & 7))]);
            }
#pragma unroll
            for (int i = 0; i < 4; ++i)
#pragma unroll
                for (int j = 0; j < 2; ++j)
                    S[i][j] = __builtin_amdgcn_mfma_f32_16x16x32_bf16(aq[i], bk[j], S[i][j], 0, 0, 0);
        }

        if constexpr (PHASE == 1) {
#pragma unroll
            for (int i = 0; i < 4; ++i)
#pragma unroll
                for (int j = 0; j < 2; ++j)
#pragma unroll
                    for (int reg = 0; reg < 4; ++reg)
                        rsum[i][reg] += __expf(S[i][j][reg] * 0.125f);
            __syncthreads();   // protect Ks before restage
        } else {
            // ---- P = exp*rinv -> bf16 stash + colsum ----
            float csacc[2] = {0.f, 0.f};
#pragma unroll
            for (int i = 0; i < 4; ++i) {
#pragma unroll
                for (int j = 0; j < 2; ++j) {
                    int kcol = wc * 32 + j * 16 + (l & 15);
#pragma unroll
                    for (int reg = 0; reg < 4; ++reg) {
                        int qrow = wr * 64 + i * 16 + (l >> 4) * 4 + reg;
                        float p = __expf(S[i][j][reg] * 0.125f) * rinv[qrow];
                        csacc[j] += p;
                        Pl[qrow * 64 + ((kcol & 7) | ((((kcol >> 3) ^ (qrow & 7))) << 3))] = f2bf(p);
                    }
                }
            }
#pragma unroll
            for (int j = 0; j < 2; ++j) {
                float v = csacc[j];
                v += __shfl_xor(v, 16);
                v += __shfl_xor(v, 32);
                if (l < 16) atomicAdd(&cs[sub * 64 + wc * 32 + j * 16 + l], v);
            }
            __syncthreads();   // Pl visible to all waves
            // ---- vectorized attn store from Pl stash (bf16-rounded fp32) ----
#pragma unroll
            for (int it2 = 0; it2 < 4; ++it2) {
                int chunk = it2 * 256 + tid;
                int row = chunk >> 3, g = chunk & 7;
                uint4 pv = Pl4[row * 8 + (g ^ (row & 7))];
                float4 lo, hi;
                lo.x = bflo2f(pv.x); lo.y = bfhi2f(pv.x);
                lo.z = bflo2f(pv.y); lo.w = bfhi2f(pv.y);
                hi.x = bflo2f(pv.z); hi.y = bfhi2f(pv.z);
                hi.z = bflo2f(pv.w); hi.w = bfhi2f(pv.w);
                float* dst = attn + hbb + (size_t)(qt * 128 + row) * B + kbase + g * 8;
                *(float4*)dst = lo;
                *(float4*)(dst + 4) = hi;
            }
            // ---- PV: O += P(128x64) @ V(64x64) ----
#pragma unroll
            for (int km = 0; km < 2; ++km) {
                int gsel = km * 4 + (l >> 4);
                bf16x8 pa[4], vb[2];
#pragma unroll
                for (int i = 0; i < 4; ++i) {
                    int q = wr * 64 + i * 16 + (l & 15);
                    pa[i] = __builtin_bit_cast(bf16x8, Pl4[q * 8 + (gsel ^ (q & 7))]);
                }
#pragma unroll
                for (int j = 0; j < 2; ++j) {
                    int d = wc * 32 + j * 16 + (l & 15);
                    vb[j] = __builtin_bit_cast(bf16x8, Vt[d * 8 + (gsel ^ (d & 7))]);
                }
#pragma unroll
                for (int i = 0; i < 4; ++i)
#pragma unroll
                    for (int j = 0; j < 2; ++j)
                        O[i][j] = __builtin_amdgcn_mfma_f32_16x16x32_bf16(pa[i], vb[j], O[i][j], 0, 0, 0);
            }
            __syncthreads();   // protect Ks/Vt/Pl before restage
        }
    }

    if constexpr (PHASE == 1) {
#pragma unroll
        for (int i = 0; i < 4; ++i)
#pragma unroll
            for (int reg = 0; reg < 4; ++reg) {
                float v = rsum[i][reg];
                v += __shfl_xor(v, 1); v += __shfl_xor(v, 2);
                v += __shfl_xor(v, 4); v += __shfl_xor(v, 8);
                if ((l & 15) == 0)
                    atomicAdd(&rowsum_out[h * B + qt * 128 + wr * 64 + i * 16 + (l >> 4) * 4 + reg], v);
            }
    } else {
        for (int i = tid; i < 512; i += 256)
            atomicAdd(&colsum[h * B + ct * 512 + i], cs[i]);
#pragma unroll
        for (int i = 0; i < 4; ++i)
#pragma unroll
            for (int j = 0; j < 2; ++j)
#pragma unroll
                for (int reg = 0; reg < 4; ++reg) {
                    int qrow = wr * 64 + i * 16 + (l >> 4) * 4 + reg;
                    ovp[((size_t)ct * B + qt * 128 + qrow) * DIM + h * 64 + wc * 32 + j * 16 + (l & 15)] =
                        O[i][j][reg];
                }
    }
}

// ---------------------------------------------------------------------------
// K4: top-5 columns per head by colsum
// ---------------------------------------------------------------------------
__global__ __launch_bounds__(256) void topk5(const float* __restrict__ colsum,
                                             int* __restrict__ topidx) {
    int h = blockIdx.x;
    __shared__ float v[B];
    __shared__ float bv[256];
    __shared__ int bi[256];
    int tid = threadIdx.x;
    for (int i = tid; i < B; i += 256) v[i] = colsum[h * B + i];
    __syncthreads();
    for (int it = 0; it < 5; ++it) {
        float best = -1e30f;
        int bidx = 0;
        for (int i = tid; i < B; i += 256) {
            float x = v[i];
            if (x > best || (x == best && i < bidx)) { best = x; bidx = i; }
        }
        bv[tid] = best; bi[tid] = bidx;
        __syncthreads();
        for (int s = 128; s > 0; s >>= 1) {
            if (tid < s) {
                if (bv[tid + s] > bv[tid] ||
                    (bv[tid + s] == bv[tid] && bi[tid + s] < bi[tid])) {
                    bv[tid] = bv[tid + s]; bi[tid] = bi[tid + s];
                }
            }
            __syncthreads();
        }
        if (tid == 0) { topidx[h * 8 + it] = bi[0]; v[bi[0]] = -1e30f; }
        __syncthreads();
    }
}

// ---------------------------------------------------------------------------
// K5: maskfix — reduce ovp partials, subtract top-5 column correction,
//     zero the masked attn columns.
// ---------------------------------------------------------------------------
__global__ __launch_bounds__(256) void maskfix(float* __restrict__ attn,
                                               const float* __restrict__ v_f32,
                                               const int* __restrict__ topidx,
                                               const float* __restrict__ ovp,
                                               float* __restrict__ ov) {
    int rt = blockIdx.x;
    int h = blockIdx.y;
    int tid = threadIdx.x;
    __shared__ float Pl[5][64];
    __shared__ float Vl[5][64];
    __shared__ int tix[5];
    if (tid < 5) tix[tid] = topidx[h * 8 + tid];
    __syncthreads();
    size_t abase = (size_t)h * B * B + (size_t)(rt * 64) * B;
    for (int t = tid; t < 320; t += 256) {
        int i = t / 64, q = t % 64;
        Pl[i][q] = attn[abase + (size_t)q * B + tix[i]];
        Vl[i][q] = v_f32[(size_t)tix[i] * DIM + h * 64 + q];
    }
    __syncthreads();
    for (int t = tid; t < 320; t += 256) {
        int i = t / 64, q = t % 64;
        attn[abase + (size_t)q * B + tix[i]] = 0.f;
    }
    int tx = tid % 16, ty = tid / 16;
    float corr[4][4] = {};
#pragma unroll
    for (int i = 0; i < 5; ++i)
#pragma unroll
        for (int a = 0; a < 4; ++a)
#pragma unroll
            for (int b2 = 0; b2 < 4; ++b2)
                corr[a][b2] += Pl[i][ty * 4 + a] * Vl[i][tx * 4 + b2];
#pragma unroll
    for (int a = 0; a < 4; ++a) {
        size_t row = (size_t)(rt * 64 + ty * 4 + a);
        size_t col = h * 64 + tx * 4;
        float4 s0 = *(const float4*)(ovp + ((size_t)0 * B + row) * DIM + col);
        float4 s1 = *(const float4*)(ovp + ((size_t)1 * B + row) * DIM + col);
        float4 s2 = *(const float4*)(ovp + ((size_t)2 * B + row) * DIM + col);
        float4 s3 = *(const float4*)(ovp + ((size_t)3 * B + row) * DIM + col);
        float4 o;
        o.x = s0.x + s1.x + s2.x + s3.x - corr[a][0];
        o.y = s0.y + s1.y + s2.y + s3.y - corr[a][1];
        o.z = s0.z + s1.z + s2.z + s3.z - corr[a][2];
        o.w = s0.w + s1.w + s2.w + s3.w - corr[a][3];
        *(float4*)(ov + row * DIM + col) = o;
    }
}

// ---------------------------------------------------------------------------
// K7: y = ov @ W_proj^T + b_proj, fused BN partial sums
// ---------------------------------------------------------------------------
__global__ __launch_bounds__(256) void proj_gemm(const float* __restrict__ ov,
                                                 const float* __restrict__ wproj,
                                                 const float* __restrict__ bproj,
                                                 float* __restrict__ y,
                                                 float* __restrict__ sums,
                                                 float* __restrict__ ssums) {
    int nt = blockIdx.x;
    int mt = blockIdx.y;
    __shared__ float As[32][68];
    __shared__ float Bs[32][68];
    __shared__ float sb[64];
    __shared__ float qb[64];
    int tid = threadIdx.x;
    int tx = tid % 16, ty = tid / 16;
    if (tid < 64) { sb[tid] = 0.f; qb[tid] = 0.f; }
    float acc[4][4] = {};
    for (int k0 = 0; k0 < 512; k0 += 32) {
        {
            int r = tid / 8;
            int c4 = (tid % 8) * 4;
#pragma unroll
            for (int p = 0; p < 2; ++p) {
                int rr = p * 32 + r;
                float4 a = *(const float4*)(ov + (size_t)(mt * 64 + rr) * DIM + k0 + c4);
                As[c4 + 0][rr] = a.x; As[c4 + 1][rr] = a.y;
                As[c4 + 2][rr] = a.z; As[c4 + 3][rr] = a.w;
                float4 b = *(const float4*)(wproj + (size_t)(nt * 64 + rr) * DIM + k0 + c4);
                Bs[c4 + 0][rr] = b.x; Bs[c4 + 1][rr] = b.y;
                Bs[c4 + 2][rr] = b.z; Bs[c4 + 3][rr] = b.w;
            }
        }
        __syncthreads();
#pragma unroll 8
        for (int kk = 0; kk < 32; ++kk) {
            float4 av = *(const float4*)&As[kk][ty * 4];
            float4 bv = *(const float4*)&Bs[kk][tx * 4];
            const float* ap = &av.x;
            const float* bp = &bv.x;
#pragma unroll
            for (int i = 0; i < 4; ++i)
#pragma unroll
                for (int j = 0; j < 4; ++j) acc[i][j] += ap[i] * bp[j];
        }
        __syncthreads();
    }
    float ls[4] = {0.f, 0.f, 0.f, 0.f};
    float lq[4] = {0.f, 0.f, 0.f, 0.f};
#pragma unroll
    for (int i = 0; i < 4; ++i) {
        float4 c;
        c.x = acc[i][0] + bproj[nt * 64 + tx * 4 + 0];
        c.y = acc[i][1] + bproj[nt * 64 + tx * 4 + 1];
        c.z = acc[i][2] + bproj[nt * 64 + tx * 4 + 2];
        c.w = acc[i][3] + bproj[nt * 64 + tx * 4 + 3];
        ls[0] += c.x; lq[0] += c.x * c.x;
        ls[1] += c.y; lq[1] += c.y * c.y;
        ls[2] += c.z; lq[2] += c.z * c.z;
        ls[3] += c.w; lq[3] += c.w * c.w;
        *(float4*)(y + (size_t)(mt * 64 + ty * 4 + i) * DIM + nt * 64 + tx * 4) = c;
    }
#pragma unroll
    for (int j = 0; j < 4; ++j) {
        atomicAdd(&sb[tx * 4 + j], ls[j]);
        atomicAdd(&qb[tx * 4 + j], lq[j]);
    }
    __syncthreads();
    if (tid < 64) {
        atomicAdd(&sums[nt * 64 + tid], sb[tid]);
        atomicAdd(&ssums[nt * 64 + tid], qb[tid]);
    }
}

// ---------------------------------------------------------------------------
// K8b: finalize mean/rstd, K9: apply+ReLU
// ---------------------------------------------------------------------------
__global__ __launch_bounds__(512) void bn_finalize(const float* __restrict__ sums,
                                                   const float* __restrict__ ssums,
                                                   float* __restrict__ mean_out,
                                                   float* __restrict__ rstd_out) {
    int c = threadIdx.x;
    float m = sums[c] * (1.0f / B);
    float var = ssums[c] * (1.0f / B) - m * m;
    mean_out[c] = m;
    rstd_out[c] = rsqrtf(var + 1e-5f);
}

__global__ __launch_bounds__(256) void bn_apply(const float* __restrict__ y,
                                                const float* __restrict__ mean,
                                                const float* __restrict__ rstd,
                                                const float* __restrict__ gamma,
                                                const float* __restrict__ beta,
                                                float* __restrict__ out) {
    int t = blockIdx.x * 256 + threadIdx.x;
    int c4 = (t % 128) * 4;
    size_t r = t / 128;
    if (r >= B) return;
    float4 v = *(const float4*)(y + r * DIM + c4);
    float4 m = *(const float4*)(mean + c4);
    float4 rs = *(const float4*)(rstd + c4);
    float4 g = *(const float4*)(gamma + c4);
    float4 bt = *(const float4*)(beta + c4);
    float4 o;
    o.x = fmaxf(0.f, g.x * (v.x - m.x) * rs.x + bt.x);
    o.y = fmaxf(0.f, g.y * (v.y - m.y) * rs.y + bt.y);
    o.z = fmaxf(0.f, g.z * (v.z - m.z) * rs.z + bt.z);
    o.w = fmaxf(0.f, g.w * (v.w - m.w) * rs.w + bt.w);
    *(float4*)(out + r * DIM + c4) = o;
}

// ---------------------------------------------------------------------------
extern "C" void kernel_launch(void* const* d_in, const int* in_sizes, int n_in,
                              void* d_out, int out_size, void* d_ws, size_t ws_size,
                              hipStream_t stream) {
    const float* x = (const float*)d_in[0];
    const float* W_qkv = (const float*)d_in[1];
    const float* W_proj = (const float*)d_in[2];
    const float* b_proj = (const float*)d_in[3];
    const float* bn_gamma = (const float*)d_in[4];
    const float* bn_beta = (const float*)d_in[5];

    float* out0 = (float*)d_out;                         // [2048,512]
    float* attn = (float*)d_out + OUT0_ELEMS;            // [8,2048,2048]

    float* ws = (float*)d_ws;
    float* v_f32 = ws;                                   // 1,048,576
    float* ovp = v_f32 + OUT0_ELEMS;                     // 4,194,304
    float* ov = ovp + 4 * OUT0_ELEMS;                    // 1,048,576
    float* y = ov + OUT0_ELEMS;                          // 1,048,576
    unsigned short* qkvbf = (unsigned short*)(y + OUT0_ELEMS);   // B*QKVN ushort
    unsigned short* vT = qkvbf + (size_t)B * QKVN;               // NH*HD*B ushort
    float* rowsum = (float*)(vT + (size_t)NH * HD * B);  // 16,384
    float* colsum = rowsum + NH * B;                     // 16,384
    float* bn_mean = colsum + NH * B;                    // 512
    float* bn_rstd = bn_mean + DIM;                      // 512
    int* topidx = (int*)(bn_rstd + DIM);                 // 64 ints
    float* sums = (float*)(topidx + 64);                 // 512
    float* ssums = sums + DIM;                           // 512
    // xbf (2 MB) + wT (1.5 MB) alias ovp: consumed by gemm_qkv_mfma, which
    // completes before attn_pass<2> writes ovp.
    unsigned short* xbf = (unsigned short*)ovp;
    unsigned short* wT = xbf + (size_t)B * 512;

    hipMemsetAsync(rowsum, 0, 2 * NH * B * sizeof(float), stream);
    hipMemsetAsync(sums, 0, 2 * DIM * sizeof(float), stream);

    cast_x<<<(B * 512 / 4) / 256, 256, 0, stream>>>(x, xbf);
    cast_wT<<<dim3(QKVN / 64, 512 / 64), 256, 0, stream>>>(W_qkv, wT);
    gemm_qkv_mfma<<<dim3(QKVN / 64, B / 128), 256, 0, stream>>>(xbf, wT, v_f32, qkvbf);
    v_transpose<<<dim3(16, NH), 256, 0, stream>>>(qkvbf, vT);
    attn_pass<1><<<dim3(4, 16, NH), 256, 0, stream>>>(qkvbf, vT, nullptr, rowsum,
                                                      attn, colsum, ovp);
    attn_pass<2><<<dim3(4, 16, NH), 256, 0, stream>>>(qkvbf, vT, rowsum, nullptr,
                                                      attn, colsum, ovp);
    topk5<<<NH, 256, 0, stream>>>(colsum, topidx);
    maskfix<<<dim3(B / 64, NH), 256, 0, stream>>>(attn, v_f32, topidx, ovp, ov);
    proj_gemm<<<dim3(DIM / 64, B / 64), 256, 0, stream>>>(ov, W_proj, b_proj, y, sums, ssums);
    bn_finalize<<<1, 512, 0, stream>>>(sums, ssums, bn_mean, bn_rstd);
    bn_apply<<<(B * DIM / 4 + 255) / 256, 256, 0, stream>>>(y, bn_mean, bn_rstd,
                                                            bn_gamma, bn_beta, out0);
}

// Round 7
// 108.455 us; speedup vs baseline: 4.6873x; 1.3341x over previous
//
#include <hip/hip_runtime.h>
#include <hip/hip_bf16.h>

#define B 2048
#define NH 8
#define HD 64
#define DIM 512
#define QKVN 1536
#define OUT0_ELEMS ((size_t)B * DIM)        // 1,048,576

typedef float f32x4 __attribute__((ext_vector_type(4)));
typedef __bf16 bf16x8 __attribute__((ext_vector_type(8)));

static __device__ __forceinline__ unsigned short f2bf(float f) {
    unsigned int u = __builtin_bit_cast(unsigned int, f);
    u += 0x7fffu + ((u >> 16) & 1u);   // RNE
    return (unsigned short)(u >> 16);
}
static __device__ __forceinline__ float bfhi2f(unsigned int u) {
    return __builtin_bit_cast(float, u & 0xffff0000u);
}
static __device__ __forceinline__ float bflo2f(unsigned int u) {
    return __builtin_bit_cast(float, u << 16);
}

// ---------------------------------------------------------------------------
// K0a: cast x (1M floats) and W_proj (256K floats) to bf16
// ---------------------------------------------------------------------------
__global__ __launch_bounds__(256) void cast_misc(const float* __restrict__ x,
                                                 const float* __restrict__ wp,
                                                 unsigned short* __restrict__ xbf,
                                                 unsigned short* __restrict__ wpbf) {
    size_t t = (size_t)blockIdx.x * 256 + threadIdx.x;
    const float4* src;
    ushort4* dst;
    size_t idx;
    if (t < 262144) { src = (const float4*)x; dst = (ushort4*)xbf; idx = t; }
    else            { src = (const float4*)wp; dst = (ushort4*)wpbf; idx = t - 262144; }
    float4 v = src[idx];
    ushort4 u;
    u.x = f2bf(v.x); u.y = f2bf(v.y); u.z = f2bf(v.z); u.w = f2bf(v.w);
    dst[idx] = u;
}

// ---------------------------------------------------------------------------
// K0b: cast + transpose W_qkv [512][1536] -> wT bf16 [1536][512]
// ---------------------------------------------------------------------------
__global__ __launch_bounds__(256) void cast_wT(const float* __restrict__ w,
                                               unsigned short* __restrict__ wT) {
    int n0 = blockIdx.x * 64;
    int k0 = blockIdx.y * 64;
    __shared__ unsigned short T[64][72];   // [n][k]
    int tid = threadIdx.x;
#pragma unroll
    for (int it = 0; it < 4; ++it) {
        int chunk = it * 256 + tid;
        int r = chunk >> 4, c4 = (chunk & 15) * 4;
        float4 v = *(const float4*)(w + (size_t)(k0 + r) * QKVN + n0 + c4);
        T[c4 + 0][r] = f2bf(v.x); T[c4 + 1][r] = f2bf(v.y);
        T[c4 + 2][r] = f2bf(v.z); T[c4 + 3][r] = f2bf(v.w);
    }
    __syncthreads();
#pragma unroll
    for (int it = 0; it < 2; ++it) {
        int chunk = it * 256 + tid;
        int r = chunk >> 3, c8 = (chunk & 7) * 8;
        ushort4 u0, u1;
        u0.x = T[r][c8 + 0]; u0.y = T[r][c8 + 1]; u0.z = T[r][c8 + 2]; u0.w = T[r][c8 + 3];
        u1.x = T[r][c8 + 4]; u1.y = T[r][c8 + 5]; u1.z = T[r][c8 + 6]; u1.w = T[r][c8 + 7];
        *(ushort4*)(wT + (size_t)(n0 + r) * 512 + k0 + c8) = u0;
        *(ushort4*)(wT + (size_t)(n0 + r) * 512 + k0 + c8 + 4) = u1;
    }
}

// ---------------------------------------------------------------------------
// K1: qkv = x @ W_qkv via bf16 MFMA. Tile 128m x 64n, 4 waves (2x2).
// q,k cols -> qkbf [B][1024]; v cols -> vT[h][d][k] (transposed, packed) + v_f32
// ---------------------------------------------------------------------------
__global__ __launch_bounds__(256) void gemm_qkv_mfma(const unsigned short* __restrict__ xbf,
                                                     const unsigned short* __restrict__ wT,
                                                     float* __restrict__ v_f32,
                                                     unsigned short* __restrict__ qkbf,
                                                     unsigned short* __restrict__ vT) {
    int nt = blockIdx.x;   // 0..23
    int mt = blockIdx.y;   // 0..15
    __shared__ uint4 Ax[128 * 8];
    __shared__ uint4 Bw[64 * 8];
    int tid = threadIdx.x;
    int l = tid & 63, wid = tid >> 6;
    int wr = wid >> 1, wc = wid & 1;
    const uint4* x4 = (const uint4*)xbf;
    const uint4* w4 = (const uint4*)wT;
    f32x4 acc[4][2];
#pragma unroll
    for (int i = 0; i < 4; ++i)
#pragma unroll
        for (int j = 0; j < 2; ++j) acc[i][j] = (f32x4){0.f, 0.f, 0.f, 0.f};

    for (int kt = 0; kt < 8; ++kt) {
        int kg = kt * 8;
#pragma unroll
        for (int it = 0; it < 4; ++it) {
            int chunk = it * 256 + tid;
            int row = chunk >> 3, slot = chunk & 7;
            Ax[row * 8 + (slot ^ (row & 7))] = x4[(size_t)(mt * 128 + row) * 64 + kg + slot];
        }
#pragma unroll
        for (int it = 0; it < 2; ++it) {
            int chunk = it * 256 + tid;
            int row = chunk >> 3, slot = chunk & 7;
            Bw[row * 8 + (slot ^ (row & 7))] = w4[(size_t)(nt * 64 + row) * 64 + kg + slot];
        }
        __syncthreads();
#pragma unroll
        for (int km = 0; km < 2; ++km) {
            int gsel = km * 4 + (l >> 4);
            bf16x8 a[4], b[2];
#pragma unroll
            for (int i = 0; i < 4; ++i) {
                int row = wr * 64 + i * 16 + (l & 15);
                a[i] = __builtin_bit_cast(bf16x8, Ax[row * 8 + (gsel ^ (row & 7))]);
            }
#pragma unroll
            for (int j = 0; j < 2; ++j) {
                int row = wc * 32 + j * 16 + (l & 15);
                b[j] = __builtin_bit_cast(bf16x8, Bw[row * 8 + (gsel ^ (row & 7))]);
            }
#pragma unroll
            for (int i = 0; i < 4; ++i)
#pragma unroll
                for (int j = 0; j < 2; ++j)
                    acc[i][j] = __builtin_amdgcn_mfma_f32_16x16x32_bf16(a[i], b[j], acc[i][j], 0, 0, 0);
        }
        __syncthreads();
    }
    if (nt < 16) {
#pragma unroll
        for (int i = 0; i < 4; ++i)
#pragma unroll
            for (int j = 0; j < 2; ++j)
#pragma unroll
                for (int reg = 0; reg < 4; ++reg) {
                    int row = mt * 128 + wr * 64 + i * 16 + (l >> 4) * 4 + reg;
                    int col = nt * 64 + wc * 32 + j * 16 + (l & 15);
                    qkbf[(size_t)row * 1024 + col] = f2bf(acc[i][j][reg]);
                }
    } else {
        int h = nt - 16;   // head
#pragma unroll
        for (int i = 0; i < 4; ++i)
#pragma unroll
            for (int j = 0; j < 2; ++j) {
                int k0r = mt * 128 + wr * 64 + i * 16 + (l >> 4) * 4;
                int d = wc * 32 + j * 16 + (l & 15);
                uint2 pk;
                pk.x = (unsigned)f2bf(acc[i][j][0]) | ((unsigned)f2bf(acc[i][j][1]) << 16);
                pk.y = (unsigned)f2bf(acc[i][j][2]) | ((unsigned)f2bf(acc[i][j][3]) << 16);
                *(uint2*)(vT + ((size_t)(h * 64 + d) * 2048 + k0r)) = pk;
#pragma unroll
                for (int reg = 0; reg < 4; ++reg)
                    v_f32[(size_t)(k0r + reg) * DIM + h * 64 + d] = acc[i][j][reg];
            }
    }
}

// ---------------------------------------------------------------------------
// K3: attention pass. PHASE 1: rowsums only. PHASE 2: recompute QK^T,
//     normalize, vector-write P (from bf16 LDS stash), colsum, PV via MFMA.
// ---------------------------------------------------------------------------
template<int PHASE>
__global__ __launch_bounds__(256) void attn_pass(const unsigned short* __restrict__ qkbf,
                                                 const unsigned short* __restrict__ vT,
                                                 const float* __restrict__ rowsum_in,
                                                 float* __restrict__ rowsum_out,
                                                 float* __restrict__ attn,
                                                 float* __restrict__ colsum,
                                                 float* __restrict__ ovp) {
    int ct = blockIdx.x, qt = blockIdx.y, h = blockIdx.z;
    int tid = threadIdx.x;
    int l = tid & 63;
    int wid = tid >> 6;
    int wr = wid >> 1;
    int wc = wid & 1;

    __shared__ uint4 Qs[128 * 8];
    __shared__ uint4 Ks[64 * 8];
    __shared__ uint4 Vt[64 * 8];
    __shared__ uint4 Pl4[128 * 8];
    __shared__ float cs[512];
    __shared__ float rinv[128];
    unsigned short* Pl = (unsigned short*)Pl4;

    const uint4* src = (const uint4*)qkbf;   // row = 128 uint4
#pragma unroll
    for (int it = 0; it < 4; ++it) {
        int chunk = it * 256 + tid;
        int row = chunk >> 3, slot = chunk & 7;
        Qs[row * 8 + (slot ^ (row & 7))] = src[(size_t)(qt * 128 + row) * 128 + h * 8 + slot];
    }
    if constexpr (PHASE == 2) {
        if (tid < 128) rinv[tid] = 1.0f / rowsum_in[h * B + qt * 128 + tid];
        if (tid < 256) { cs[tid] = 0.f; cs[tid + 256] = 0.f; }
    }

    float rsum[4][4];
    f32x4 O[4][2];
    if constexpr (PHASE == 1) {
#pragma unroll
        for (int i = 0; i < 4; ++i)
#pragma unroll
            for (int r = 0; r < 4; ++r) rsum[i][r] = 0.f;
    } else {
#pragma unroll
        for (int i = 0; i < 4; ++i)
#pragma unroll
            for (int j = 0; j < 2; ++j) O[i][j] = (f32x4){0.f, 0.f, 0.f, 0.f};
    }

    size_t hbb = (size_t)h * B * B;
    for (int sub = 0; sub < 8; ++sub) {
        int kbase = ct * 512 + sub * 64;
#pragma unroll
        for (int it = 0; it < 2; ++it) {
            int chunk = it * 256 + tid;
            int row = chunk >> 3, slot = chunk & 7;
            Ks[row * 8 + (slot ^ (row & 7))] = src[(size_t)(kbase + row) * 128 + 64 + h * 8 + slot];
        }
        if constexpr (PHASE == 2) {
#pragma unroll
            for (int it = 0; it < 2; ++it) {
                int chunk = it * 256 + tid;
                int d = chunk >> 3, g = chunk & 7;
                Vt[d * 8 + (g ^ (d & 7))] =
                    *(const uint4*)(vT + ((size_t)(h * 64 + d) * 2048 + kbase + g * 8));
            }
        }
        __syncthreads();

        // ---- QK^T ----
        f32x4 S[4][2];
#pragma unroll
        for (int i = 0; i < 4; ++i)
#pragma unroll
            for (int j = 0; j < 2; ++j) S[i][j] = (f32x4){0.f, 0.f, 0.f, 0.f};
#pragma unroll
        for (int km = 0; km < 2; ++km) {
            int gsel = km * 4 + (l >> 4);
            bf16x8 aq[4], bk[2];
#pragma unroll
            for (int i = 0; i < 4; ++i) {
                int row = wr * 64 + i * 16 + (l & 15);
                aq[i] = __builtin_bit_cast(bf16x8, Qs[row * 8 + (gsel ^ (row & 7))]);
            }
#pragma unroll
            for (int j = 0; j < 2; ++j) {
                int row = wc * 32 + j * 16 + (l & 15);
                bk[j] = __builtin_bit_cast(bf16x8, Ks[row * 8 + (gsel ^ (row & 7))]);
            }
#pragma unroll
            for (int i = 0; i < 4; ++i)
#pragma unroll
                for (int j = 0; j < 2; ++j)
                    S[i][j] = __builtin_amdgcn_mfma_f32_16x16x32_bf16(aq[i], bk[j], S[i][j], 0, 0, 0);
        }

        if constexpr (PHASE == 1) {
#pragma unroll
            for (int i = 0; i < 4; ++i)
#pragma unroll
                for (int j = 0; j < 2; ++j)
#pragma unroll
                    for (int reg = 0; reg < 4; ++reg)
                        rsum[i][reg] += __expf(S[i][j][reg] * 0.125f);
            __syncthreads();
        } else {
            float csacc[2] = {0.f, 0.f};
#pragma unroll
            for (int i = 0; i < 4; ++i) {
#pragma unroll
                for (int j = 0; j < 2; ++j) {
                    int kcol = wc * 32 + j * 16 + (l & 15);
#pragma unroll
                    for (int reg = 0; reg < 4; ++reg) {
                        int qrow = wr * 64 + i * 16 + (l >> 4) * 4 + reg;
                        float p = __expf(S[i][j][reg] * 0.125f) * rinv[qrow];
                        csacc[j] += p;
                        Pl[qrow * 64 + ((kcol & 7) | ((((kcol >> 3) ^ (qrow & 7))) << 3))] = f2bf(p);
                    }
                }
            }
#pragma unroll
            for (int j = 0; j < 2; ++j) {
                float v = csacc[j];
                v += __shfl_xor(v, 16);
                v += __shfl_xor(v, 32);
                if (l < 16) atomicAdd(&cs[sub * 64 + wc * 32 + j * 16 + l], v);
            }
            __syncthreads();
#pragma unroll
            for (int it2 = 0; it2 < 4; ++it2) {
                int chunk = it2 * 256 + tid;
                int row = chunk >> 3, g = chunk & 7;
                uint4 pv = Pl4[row * 8 + (g ^ (row & 7))];
                float4 lo, hi;
                lo.x = bflo2f(pv.x); lo.y = bfhi2f(pv.x);
                lo.z = bflo2f(pv.y); lo.w = bfhi2f(pv.y);
                hi.x = bflo2f(pv.z); hi.y = bfhi2f(pv.z);
                hi.z = bflo2f(pv.w); hi.w = bfhi2f(pv.w);
                float* dst = attn + hbb + (size_t)(qt * 128 + row) * B + kbase + g * 8;
                *(float4*)dst = lo;
                *(float4*)(dst + 4) = hi;
            }
#pragma unroll
            for (int km = 0; km < 2; ++km) {
                int gsel = km * 4 + (l >> 4);
                bf16x8 pa[4], vb[2];
#pragma unroll
                for (int i = 0; i < 4; ++i) {
                    int q = wr * 64 + i * 16 + (l & 15);
                    pa[i] = __builtin_bit_cast(bf16x8, Pl4[q * 8 + (gsel ^ (q & 7))]);
                }
#pragma unroll
                for (int j = 0; j < 2; ++j) {
                    int d = wc * 32 + j * 16 + (l & 15);
                    vb[j] = __builtin_bit_cast(bf16x8, Vt[d * 8 + (gsel ^ (d & 7))]);
                }
#pragma unroll
                for (int i = 0; i < 4; ++i)
#pragma unroll
                    for (int j = 0; j < 2; ++j)
                        O[i][j] = __builtin_amdgcn_mfma_f32_16x16x32_bf16(pa[i], vb[j], O[i][j], 0, 0, 0);
            }
            __syncthreads();
        }
    }

    if constexpr (PHASE == 1) {
#pragma unroll
        for (int i = 0; i < 4; ++i)
#pragma unroll
            for (int reg = 0; reg < 4; ++reg) {
                float v = rsum[i][reg];
                v += __shfl_xor(v, 1); v += __shfl_xor(v, 2);
                v += __shfl_xor(v, 4); v += __shfl_xor(v, 8);
                if ((l & 15) == 0)
                    atomicAdd(&rowsum_out[h * B + qt * 128 + wr * 64 + i * 16 + (l >> 4) * 4 + reg], v);
            }
    } else {
        for (int i = tid; i < 512; i += 256)
            atomicAdd(&colsum[h * B + ct * 512 + i], cs[i]);
#pragma unroll
        for (int i = 0; i < 4; ++i)
#pragma unroll
            for (int j = 0; j < 2; ++j)
#pragma unroll
                for (int reg = 0; reg < 4; ++reg) {
                    int qrow = wr * 64 + i * 16 + (l >> 4) * 4 + reg;
                    ovp[((size_t)ct * B + qt * 128 + qrow) * DIM + h * 64 + wc * 32 + j * 16 + (l & 15)] =
                        O[i][j][reg];
                }
    }
}

// ---------------------------------------------------------------------------
// K4: top-5 columns per head by colsum
// ---------------------------------------------------------------------------
__global__ __launch_bounds__(256) void topk5(const float* __restrict__ colsum,
                                             int* __restrict__ topidx) {
    int h = blockIdx.x;
    __shared__ float v[B];
    __shared__ float bv[256];
    __shared__ int bi[256];
    int tid = threadIdx.x;
    for (int i = tid; i < B; i += 256) v[i] = colsum[h * B + i];
    __syncthreads();
    for (int it = 0; it < 5; ++it) {
        float best = -1e30f;
        int bidx = 0;
        for (int i = tid; i < B; i += 256) {
            float x = v[i];
            if (x > best || (x == best && i < bidx)) { best = x; bidx = i; }
        }
        bv[tid] = best; bi[tid] = bidx;
        __syncthreads();
        for (int s = 128; s > 0; s >>= 1) {
            if (tid < s) {
                if (bv[tid + s] > bv[tid] ||
                    (bv[tid + s] == bv[tid] && bi[tid + s] < bi[tid])) {
                    bv[tid] = bv[tid + s]; bi[tid] = bi[tid + s];
                }
            }
            __syncthreads();
        }
        if (tid == 0) { topidx[h * 8 + it] = bi[0]; v[bi[0]] = -1e30f; }
        __syncthreads();
    }
}

// ---------------------------------------------------------------------------
// K5: maskfix — reduce ovp partials, subtract top-5 column correction,
//     zero masked attn columns, emit ov in bf16 for the proj MFMA.
// ---------------------------------------------------------------------------
__global__ __launch_bounds__(256) void maskfix(float* __restrict__ attn,
                                               const float* __restrict__ v_f32,
                                               const int* __restrict__ topidx,
                                               const float* __restrict__ ovp,
                                               unsigned short* __restrict__ ovbf) {
    int rt = blockIdx.x;
    int h = blockIdx.y;
    int tid = threadIdx.x;
    __shared__ float Pl[5][64];
    __shared__ float Vl[5][64];
    __shared__ int tix[5];
    if (tid < 5) tix[tid] = topidx[h * 8 + tid];
    __syncthreads();
    size_t abase = (size_t)h * B * B + (size_t)(rt * 64) * B;
    for (int t = tid; t < 320; t += 256) {
        int i = t / 64, q = t % 64;
        Pl[i][q] = attn[abase + (size_t)q * B + tix[i]];
        Vl[i][q] = v_f32[(size_t)tix[i] * DIM + h * 64 + q];
    }
    __syncthreads();
    for (int t = tid; t < 320; t += 256) {
        int i = t / 64, q = t % 64;
        attn[abase + (size_t)q * B + tix[i]] = 0.f;
    }
    int tx = tid % 16, ty = tid / 16;
    float corr[4][4] = {};
#pragma unroll
    for (int i = 0; i < 5; ++i)
#pragma unroll
        for (int a = 0; a < 4; ++a)
#pragma unroll
            for (int b2 = 0; b2 < 4; ++b2)
                corr[a][b2] += Pl[i][ty * 4 + a] * Vl[i][tx * 4 + b2];
#pragma unroll
    for (int a = 0; a < 4; ++a) {
        size_t row = (size_t)(rt * 64 + ty * 4 + a);
        size_t col = h * 64 + tx * 4;
        float4 s0 = *(const float4*)(ovp + ((size_t)0 * B + row) * DIM + col);
        float4 s1 = *(const float4*)(ovp + ((size_t)1 * B + row) * DIM + col);
        float4 s2 = *(const float4*)(ovp + ((size_t)2 * B + row) * DIM + col);
        float4 s3 = *(const float4*)(ovp + ((size_t)3 * B + row) * DIM + col);
        ushort4 u;
        u.x = f2bf(s0.x + s1.x + s2.x + s3.x - corr[a][0]);
        u.y = f2bf(s0.y + s1.y + s2.y + s3.y - corr[a][1]);
        u.z = f2bf(s0.z + s1.z + s2.z + s3.z - corr[a][2]);
        u.w = f2bf(s0.w + s1.w + s2.w + s3.w - corr[a][3]);
        *(ushort4*)(ovbf + row * DIM + col) = u;
    }
}

// ---------------------------------------------------------------------------
// K7: y = ov @ W_proj^T + b_proj via bf16 MFMA; fused BN partial sums.
// W_proj is [j][d] row-major == B-fragment layout (k-contiguous per out col).
// ---------------------------------------------------------------------------
__global__ __launch_bounds__(256) void proj_gemm_mfma(const unsigned short* __restrict__ ovbf,
                                                      const unsigned short* __restrict__ wpbf,
                                                      const float* __restrict__ bproj,
                                                      float* __restrict__ y,
                                                      float* __restrict__ sums,
                                                      float* __restrict__ ssums) {
    int nt = blockIdx.x;   // 0..7
    int mt = blockIdx.y;   // 0..15
    __shared__ uint4 Ax[128 * 8];
    __shared__ uint4 Bw[64 * 8];
    __shared__ float sb[64];
    __shared__ float qb[64];
    int tid = threadIdx.x;
    int l = tid & 63, wid = tid >> 6;
    int wr = wid >> 1, wc = wid & 1;
    if (tid < 64) { sb[tid] = 0.f; qb[tid] = 0.f; }
    const uint4* a4 = (const uint4*)ovbf;   // row stride 64 uint4
    const uint4* b4 = (const uint4*)wpbf;
    f32x4 acc[4][2];
#pragma unroll
    for (int i = 0; i < 4; ++i)
#pragma unroll
        for (int j = 0; j < 2; ++j) acc[i][j] = (f32x4){0.f, 0.f, 0.f, 0.f};

    for (int kt = 0; kt < 8; ++kt) {
        int kg = kt * 8;
#pragma unroll
        for (int it = 0; it < 4; ++it) {
            int chunk = it * 256 + tid;
            int row = chunk >> 3, slot = chunk & 7;
            Ax[row * 8 + (slot ^ (row & 7))] = a4[(size_t)(mt * 128 + row) * 64 + kg + slot];
        }
#pragma unroll
        for (int it = 0; it < 2; ++it) {
            int chunk = it * 256 + tid;
            int row = chunk >> 3, slot = chunk & 7;
            Bw[row * 8 + (slot ^ (row & 7))] = b4[(size_t)(nt * 64 + row) * 64 + kg + slot];
        }
        __syncthreads();
#pragma unroll
        for (int km = 0; km < 2; ++km) {
            int gsel = km * 4 + (l >> 4);
            bf16x8 a[4], b[2];
#pragma unroll
            for (int i = 0; i < 4; ++i) {
                int row = wr * 64 + i * 16 + (l & 15);
                a[i] = __builtin_bit_cast(bf16x8, Ax[row * 8 + (gsel ^ (row & 7))]);
            }
#pragma unroll
            for (int j = 0; j < 2; ++j) {
                int row = wc * 32 + j * 16 + (l & 15);
                b[j] = __builtin_bit_cast(bf16x8, Bw[row * 8 + (gsel ^ (row & 7))]);
            }
#pragma unroll
            for (int i = 0; i < 4; ++i)
#pragma unroll
                for (int j = 0; j < 2; ++j)
                    acc[i][j] = __builtin_amdgcn_mfma_f32_16x16x32_bf16(a[i], b[j], acc[i][j], 0, 0, 0);
        }
        __syncthreads();
    }
    float ls[2] = {0.f, 0.f};
    float lq[2] = {0.f, 0.f};
#pragma unroll
    for (int i = 0; i < 4; ++i)
#pragma unroll
        for (int j = 0; j < 2; ++j) {
            int col = nt * 64 + wc * 32 + j * 16 + (l & 15);
            float bp = bproj[col];
#pragma unroll
            for (int reg = 0; reg < 4; ++reg) {
                int row = mt * 128 + wr * 64 + i * 16 + (l >> 4) * 4 + reg;
                float c = acc[i][j][reg] + bp;
                y[(size_t)row * DIM + col] = c;
                ls[j] += c; lq[j] += c * c;
            }
        }
#pragma unroll
    for (int j = 0; j < 2; ++j) {
        atomicAdd(&sb[wc * 32 + j * 16 + (l & 15)], ls[j]);
        atomicAdd(&qb[wc * 32 + j * 16 + (l & 15)], lq[j]);
    }
    __syncthreads();
    if (tid < 64) {
        atomicAdd(&sums[nt * 64 + tid], sb[tid]);
        atomicAdd(&ssums[nt * 64 + tid], qb[tid]);
    }
}

// ---------------------------------------------------------------------------
// K9: out = relu(gamma*(y-mean)*rstd + beta); mean/rstd from sums inline
// ---------------------------------------------------------------------------
__global__ __launch_bounds__(256) void bn_apply(const float* __restrict__ y,
                                                const float* __restrict__ sums,
                                                const float* __restrict__ ssums,
                                                const float* __restrict__ gamma,
                                                const float* __restrict__ beta,
                                                float* __restrict__ out) {
    int t = blockIdx.x * 256 + threadIdx.x;
    int c4 = (t % 128) * 4;
    size_t r = t / 128;
    if (r >= B) return;
    float4 s = *(const float4*)(sums + c4);
    float4 q = *(const float4*)(ssums + c4);
    float4 m, rs;
    m.x = s.x * (1.0f / B); m.y = s.y * (1.0f / B);
    m.z = s.z * (1.0f / B); m.w = s.w * (1.0f / B);
    rs.x = rsqrtf(q.x * (1.0f / B) - m.x * m.x + 1e-5f);
    rs.y = rsqrtf(q.y * (1.0f / B) - m.y * m.y + 1e-5f);
    rs.z = rsqrtf(q.z * (1.0f / B) - m.z * m.z + 1e-5f);
    rs.w = rsqrtf(q.w * (1.0f / B) - m.w * m.w + 1e-5f);
    float4 v = *(const float4*)(y + r * DIM + c4);
    float4 g = *(const float4*)(gamma + c4);
    float4 bt = *(const float4*)(beta + c4);
    float4 o;
    o.x = fmaxf(0.f, g.x * (v.x - m.x) * rs.x + bt.x);
    o.y = fmaxf(0.f, g.y * (v.y - m.y) * rs.y + bt.y);
    o.z = fmaxf(0.f, g.z * (v.z - m.z) * rs.z + bt.z);
    o.w = fmaxf(0.f, g.w * (v.w - m.w) * rs.w + bt.w);
    *(float4*)(out + r * DIM + c4) = o;
}

// ---------------------------------------------------------------------------
extern "C" void kernel_launch(void* const* d_in, const int* in_sizes, int n_in,
                              void* d_out, int out_size, void* d_ws, size_t ws_size,
                              hipStream_t stream) {
    const float* x = (const float*)d_in[0];
    const float* W_qkv = (const float*)d_in[1];
    const float* W_proj = (const float*)d_in[2];
    const float* b_proj = (const float*)d_in[3];
    const float* bn_gamma = (const float*)d_in[4];
    const float* bn_beta = (const float*)d_in[5];

    float* out0 = (float*)d_out;                         // [2048,512]
    float* attn = (float*)d_out + OUT0_ELEMS;            // [8,2048,2048]

    float* ws = (float*)d_ws;
    float* v_f32 = ws;                                   // 1,048,576 f
    float* ovp = v_f32 + OUT0_ELEMS;                     // 4,194,304 f
    float* y = ovp + 4 * OUT0_ELEMS;                     // 1,048,576 f
    // zero region (contiguous, one memset): rowsum, colsum, sums, ssums
    float* rowsum = y + OUT0_ELEMS;                      // 16,384 f
    float* colsum = rowsum + NH * B;                     // 16,384 f
    float* sums = colsum + NH * B;                       // 512 f
    float* ssums = sums + DIM;                           // 512 f
    int* topidx = (int*)(ssums + DIM);                   // 64 ints
    unsigned short* qkbf = (unsigned short*)(topidx + 64);       // B*1024 us
    unsigned short* vT = qkbf + (size_t)B * 1024;                // NH*HD*B us
    unsigned short* wpbf = vT + (size_t)NH * HD * B;             // 512*512 us
    unsigned short* ovbf = wpbf + (size_t)DIM * DIM;             // B*DIM us
    // xbf (2 MB) + wT (1.5 MB) alias ovp: consumed by gemm_qkv_mfma, which
    // completes before attn_pass<2> writes ovp.
    unsigned short* xbf = (unsigned short*)ovp;
    unsigned short* wT = xbf + (size_t)B * 512;

    hipMemsetAsync(rowsum, 0, (2 * NH * B + 2 * DIM) * sizeof(float), stream);

    cast_misc<<<(262144 + 65536) / 256, 256, 0, stream>>>(x, W_proj, xbf, wpbf);
    cast_wT<<<dim3(QKVN / 64, 512 / 64), 256, 0, stream>>>(W_qkv, wT);
    gemm_qkv_mfma<<<dim3(QKVN / 64, B / 128), 256, 0, stream>>>(xbf, wT, v_f32, qkbf, vT);
    attn_pass<1><<<dim3(4, 16, NH), 256, 0, stream>>>(qkbf, vT, nullptr, rowsum,
                                                      attn, colsum, ovp);
    attn_pass<2><<<dim3(4, 16, NH), 256, 0, stream>>>(qkbf, vT, rowsum, nullptr,
                                                      attn, colsum, ovp);
    topk5<<<NH, 256, 0, stream>>>(colsum, topidx);
    maskfix<<<dim3(B / 64, NH), 256, 0, stream>>>(attn, v_f32, topidx, ovp, ovbf);
    proj_gemm_mfma<<<dim3(DIM / 64, B / 128), 256, 0, stream>>>(ovbf, wpbf, b_proj,
                                                                y, sums, ssums);
    bn_apply<<<(B * DIM / 4 + 255) / 256, 256, 0, stream>>>(y, sums, ssums,
                                                            bn_gamma, bn_beta, out0);
}

// Round 9
// 104.540 us; speedup vs baseline: 4.8628x; 1.0374x over previous
//
#include <hip/hip_runtime.h>
#include <hip/hip_bf16.h>

#define B 2048
#define NH 8
#define HD 64
#define DIM 512
#define QKVN 1536
#define OUT0_ELEMS ((size_t)B * DIM)        // 1,048,576

typedef float f32x4 __attribute__((ext_vector_type(4)));
typedef __bf16 bf16x8 __attribute__((ext_vector_type(8)));

static __device__ __forceinline__ unsigned short f2bf(float f) {
    unsigned int u = __builtin_bit_cast(unsigned int, f);
    u += 0x7fffu + ((u >> 16) & 1u);   // RNE
    return (unsigned short)(u >> 16);
}
static __device__ __forceinline__ float bfhi2f(unsigned int u) {
    return __builtin_bit_cast(float, u & 0xffff0000u);
}
static __device__ __forceinline__ float bflo2f(unsigned int u) {
    return __builtin_bit_cast(float, u << 16);
}

// ---------------------------------------------------------------------------
// K0: all input casts in one launch.
// blocks [0,1280): x (1M) + W_proj (256K) flat cast
// blocks [1280,1472): W_qkv cast+transpose -> wT [1536][512]
// ---------------------------------------------------------------------------
__global__ __launch_bounds__(256) void prep_cast(const float* __restrict__ x,
                                                 const float* __restrict__ wp,
                                                 const float* __restrict__ wqkv,
                                                 unsigned short* __restrict__ xbf,
                                                 unsigned short* __restrict__ wpbf,
                                                 unsigned short* __restrict__ wT) {
    int bx = blockIdx.x;
    int tid = threadIdx.x;
    if (bx < 1280) {
        size_t t = (size_t)bx * 256 + tid;
        const float4* src;
        ushort4* dst;
        size_t idx;
        if (t < 262144) { src = (const float4*)x; dst = (ushort4*)xbf; idx = t; }
        else            { src = (const float4*)wp; dst = (ushort4*)wpbf; idx = t - 262144; }
        float4 v = src[idx];
        ushort4 u;
        u.x = f2bf(v.x); u.y = f2bf(v.y); u.z = f2bf(v.z); u.w = f2bf(v.w);
        dst[idx] = u;
        return;
    }
    int b = bx - 1280;                 // 0..191
    int n0 = (b % 24) * 64;
    int k0 = (b / 24) * 64;
    __shared__ unsigned short T[64][72];   // [n][k]
#pragma unroll
    for (int it = 0; it < 4; ++it) {
        int chunk = it * 256 + tid;
        int r = chunk >> 4, c4 = (chunk & 15) * 4;
        float4 v = *(const float4*)(wqkv + (size_t)(k0 + r) * QKVN + n0 + c4);
        T[c4 + 0][r] = f2bf(v.x); T[c4 + 1][r] = f2bf(v.y);
        T[c4 + 2][r] = f2bf(v.z); T[c4 + 3][r] = f2bf(v.w);
    }
    __syncthreads();
#pragma unroll
    for (int it = 0; it < 2; ++it) {
        int chunk = it * 256 + tid;
        int r = chunk >> 3, c8 = (chunk & 7) * 8;
        ushort4 u0, u1;
        u0.x = T[r][c8 + 0]; u0.y = T[r][c8 + 1]; u0.z = T[r][c8 + 2]; u0.w = T[r][c8 + 3];
        u1.x = T[r][c8 + 4]; u1.y = T[r][c8 + 5]; u1.z = T[r][c8 + 6]; u1.w = T[r][c8 + 7];
        *(ushort4*)(wT + (size_t)(n0 + r) * 512 + k0 + c8) = u0;
        *(ushort4*)(wT + (size_t)(n0 + r) * 512 + k0 + c8 + 4) = u1;
    }
}

// ---------------------------------------------------------------------------
// K1: qkv = x @ W_qkv via bf16 MFMA. Tile 128m x 64n, 4 waves (2x2).
// q,k cols -> qkbf [B][1024]; v cols -> vT[h][d][k] (transposed) + v_f32
// ---------------------------------------------------------------------------
__global__ __launch_bounds__(256) void gemm_qkv_mfma(const unsigned short* __restrict__ xbf,
                                                     const unsigned short* __restrict__ wT,
                                                     float* __restrict__ v_f32,
                                                     unsigned short* __restrict__ qkbf,
                                                     unsigned short* __restrict__ vT) {
    int nt = blockIdx.x;   // 0..23
    int mt = blockIdx.y;   // 0..15
    __shared__ uint4 Ax[128 * 8];
    __shared__ uint4 Bw[64 * 8];
    int tid = threadIdx.x;
    int l = tid & 63, wid = tid >> 6;
    int wr = wid >> 1, wc = wid & 1;
    const uint4* x4 = (const uint4*)xbf;
    const uint4* w4 = (const uint4*)wT;
    f32x4 acc[4][2];
#pragma unroll
    for (int i = 0; i < 4; ++i)
#pragma unroll
        for (int j = 0; j < 2; ++j) acc[i][j] = (f32x4){0.f, 0.f, 0.f, 0.f};

    for (int kt = 0; kt < 8; ++kt) {
        int kg = kt * 8;
#pragma unroll
        for (int it = 0; it < 4; ++it) {
            int chunk = it * 256 + tid;
            int row = chunk >> 3, slot = chunk & 7;
            Ax[row * 8 + (slot ^ (row & 7))] = x4[(size_t)(mt * 128 + row) * 64 + kg + slot];
        }
#pragma unroll
        for (int it = 0; it < 2; ++it) {
            int chunk = it * 256 + tid;
            int row = chunk >> 3, slot = chunk & 7;
            Bw[row * 8 + (slot ^ (row & 7))] = w4[(size_t)(nt * 64 + row) * 64 + kg + slot];
        }
        __syncthreads();
#pragma unroll
        for (int km = 0; km < 2; ++km) {
            int gsel = km * 4 + (l >> 4);
            bf16x8 a[4], b[2];
#pragma unroll
            for (int i = 0; i < 4; ++i) {
                int row = wr * 64 + i * 16 + (l & 15);
                a[i] = __builtin_bit_cast(bf16x8, Ax[row * 8 + (gsel ^ (row & 7))]);
            }
#pragma unroll
            for (int j = 0; j < 2; ++j) {
                int row = wc * 32 + j * 16 + (l & 15);
                b[j] = __builtin_bit_cast(bf16x8, Bw[row * 8 + (gsel ^ (row & 7))]);
            }
#pragma unroll
            for (int i = 0; i < 4; ++i)
#pragma unroll
                for (int j = 0; j < 2; ++j)
                    acc[i][j] = __builtin_amdgcn_mfma_f32_16x16x32_bf16(a[i], b[j], acc[i][j], 0, 0, 0);
        }
        __syncthreads();
    }
    if (nt < 16) {
#pragma unroll
        for (int i = 0; i < 4; ++i)
#pragma unroll
            for (int j = 0; j < 2; ++j)
#pragma unroll
                for (int reg = 0; reg < 4; ++reg) {
                    int row = mt * 128 + wr * 64 + i * 16 + (l >> 4) * 4 + reg;
                    int col = nt * 64 + wc * 32 + j * 16 + (l & 15);
                    qkbf[(size_t)row * 1024 + col] = f2bf(acc[i][j][reg]);
                }
    } else {
        int h = nt - 16;   // head
#pragma unroll
        for (int i = 0; i < 4; ++i)
#pragma unroll
            for (int j = 0; j < 2; ++j) {
                int k0r = mt * 128 + wr * 64 + i * 16 + (l >> 4) * 4;
                int d = wc * 32 + j * 16 + (l & 15);
                uint2 pk;
                pk.x = (unsigned)f2bf(acc[i][j][0]) | ((unsigned)f2bf(acc[i][j][1]) << 16);
                pk.y = (unsigned)f2bf(acc[i][j][2]) | ((unsigned)f2bf(acc[i][j][3]) << 16);
                *(uint2*)(vT + ((size_t)(h * 64 + d) * 2048 + k0r)) = pk;
#pragma unroll
                for (int reg = 0; reg < 4; ++reg)
                    v_f32[(size_t)(k0r + reg) * DIM + h * 64 + d] = acc[i][j][reg];
            }
    }
}

// ---------------------------------------------------------------------------
// K3: attention pass. PHASE 1: rowsums only. PHASE 2: recompute QK^T,
//     normalize, vector-write P (from bf16 LDS stash), colsum, PV via MFMA.
// ---------------------------------------------------------------------------
template<int PHASE>
__global__ __launch_bounds__(256) void attn_pass(const unsigned short* __restrict__ qkbf,
                                                 const unsigned short* __restrict__ vT,
                                                 const float* __restrict__ rowsum_in,
                                                 float* __restrict__ rowsum_out,
                                                 float* __restrict__ attn,
                                                 float* __restrict__ colsum,
                                                 float* __restrict__ ovp) {
    int ct = blockIdx.x, qt = blockIdx.y, h = blockIdx.z;
    int tid = threadIdx.x;
    int l = tid & 63;
    int wid = tid >> 6;
    int wr = wid >> 1;
    int wc = wid & 1;

    __shared__ uint4 Qs[128 * 8];
    __shared__ uint4 Ks[64 * 8];
    __shared__ uint4 Vt[64 * 8];
    __shared__ uint4 Pl4[128 * 8];
    __shared__ float cs[512];
    __shared__ float rinv[128];
    unsigned short* Pl = (unsigned short*)Pl4;

    const uint4* src = (const uint4*)qkbf;   // row = 128 uint4
#pragma unroll
    for (int it = 0; it < 4; ++it) {
        int chunk = it * 256 + tid;
        int row = chunk >> 3, slot = chunk & 7;
        Qs[row * 8 + (slot ^ (row & 7))] = src[(size_t)(qt * 128 + row) * 128 + h * 8 + slot];
    }
    if constexpr (PHASE == 2) {
        if (tid < 128) rinv[tid] = 1.0f / rowsum_in[h * B + qt * 128 + tid];
        if (tid < 256) { cs[tid] = 0.f; cs[tid + 256] = 0.f; }
    }

    float rsum[4][4];
    f32x4 O[4][2];
    if constexpr (PHASE == 1) {
#pragma unroll
        for (int i = 0; i < 4; ++i)
#pragma unroll
            for (int r = 0; r < 4; ++r) rsum[i][r] = 0.f;
    } else {
#pragma unroll
        for (int i = 0; i < 4; ++i)
#pragma unroll
            for (int j = 0; j < 2; ++j) O[i][j] = (f32x4){0.f, 0.f, 0.f, 0.f};
    }

    size_t hbb = (size_t)h * B * B;
    for (int sub = 0; sub < 8; ++sub) {
        int kbase = ct * 512 + sub * 64;
#pragma unroll
        for (int it = 0; it < 2; ++it) {
            int chunk = it * 256 + tid;
            int row = chunk >> 3, slot = chunk & 7;
            Ks[row * 8 + (slot ^ (row & 7))] = src[(size_t)(kbase + row) * 128 + 64 + h * 8 + slot];
        }
        if constexpr (PHASE == 2) {
#pragma unroll
            for (int it = 0; it < 2; ++it) {
                int chunk = it * 256 + tid;
                int d = chunk >> 3, g = chunk & 7;
                Vt[d * 8 + (g ^ (d & 7))] =
                    *(const uint4*)(vT + ((size_t)(h * 64 + d) * 2048 + kbase + g * 8));
            }
        }
        __syncthreads();

        // ---- QK^T ----
        f32x4 S[4][2];
#pragma unroll
        for (int i = 0; i < 4; ++i)
#pragma unroll
            for (int j = 0; j < 2; ++j) S[i][j] = (f32x4){0.f, 0.f, 0.f, 0.f};
#pragma unroll
        for (int km = 0; km < 2; ++km) {
            int gsel = km * 4 + (l >> 4);
            bf16x8 aq[4], bk[2];
#pragma unroll
            for (int i = 0; i < 4; ++i) {
                int row = wr * 64 + i * 16 + (l & 15);
                aq[i] = __builtin_bit_cast(bf16x8, Qs[row * 8 + (gsel ^ (row & 7))]);
            }
#pragma unroll
            for (int j = 0; j < 2; ++j) {
                int row = wc * 32 + j * 16 + (l & 15);
                bk[j] = __builtin_bit_cast(bf16x8, Ks[row * 8 + (gsel ^ (row & 7))]);
            }
#pragma unroll
            for (int i = 0; i < 4; ++i)
#pragma unroll
                for (int j = 0; j < 2; ++j)
                    S[i][j] = __builtin_amdgcn_mfma_f32_16x16x32_bf16(aq[i], bk[j], S[i][j], 0, 0, 0);
        }

        if constexpr (PHASE == 1) {
#pragma unroll
            for (int i = 0; i < 4; ++i)
#pragma unroll
                for (int j = 0; j < 2; ++j)
#pragma unroll
                    for (int reg = 0; reg < 4; ++reg)
                        rsum[i][reg] += __expf(S[i][j][reg] * 0.125f);
            __syncthreads();
        } else {
            float csacc[2] = {0.f, 0.f};
#pragma unroll
            for (int i = 0; i < 4; ++i) {
#pragma unroll
                for (int j = 0; j < 2; ++j) {
                    int kcol = wc * 32 + j * 16 + (l & 15);
#pragma unroll
                    for (int reg = 0; reg < 4; ++reg) {
                        int qrow = wr * 64 + i * 16 + (l >> 4) * 4 + reg;
                        float p = __expf(S[i][j][reg] * 0.125f) * rinv[qrow];
                        csacc[j] += p;
                        Pl[qrow * 64 + ((kcol & 7) | ((((kcol >> 3) ^ (qrow & 7))) << 3))] = f2bf(p);
                    }
                }
            }
#pragma unroll
            for (int j = 0; j < 2; ++j) {
                float v = csacc[j];
                v += __shfl_xor(v, 16);
                v += __shfl_xor(v, 32);
                if (l < 16) atomicAdd(&cs[sub * 64 + wc * 32 + j * 16 + l], v);
            }
            __syncthreads();
#pragma unroll
            for (int it2 = 0; it2 < 4; ++it2) {
                int chunk = it2 * 256 + tid;
                int row = chunk >> 3, g = chunk & 7;
                uint4 pv = Pl4[row * 8 + (g ^ (row & 7))];
                float4 lo, hi;
                lo.x = bflo2f(pv.x); lo.y = bfhi2f(pv.x);
                lo.z = bflo2f(pv.y); lo.w = bfhi2f(pv.y);
                hi.x = bflo2f(pv.z); hi.y = bfhi2f(pv.z);
                hi.z = bflo2f(pv.w); hi.w = bfhi2f(pv.w);
                float* dst = attn + hbb + (size_t)(qt * 128 + row) * B + kbase + g * 8;
                *(float4*)dst = lo;
                *(float4*)(dst + 4) = hi;
            }
#pragma unroll
            for (int km = 0; km < 2; ++km) {
                int gsel = km * 4 + (l >> 4);
                bf16x8 pa[4], vb[2];
#pragma unroll
                for (int i = 0; i < 4; ++i) {
                    int q = wr * 64 + i * 16 + (l & 15);
                    pa[i] = __builtin_bit_cast(bf16x8, Pl4[q * 8 + (gsel ^ (q & 7))]);
                }
#pragma unroll
                for (int j = 0; j < 2; ++j) {
                    int d = wc * 32 + j * 16 + (l & 15);
                    vb[j] = __builtin_bit_cast(bf16x8, Vt[d * 8 + (gsel ^ (d & 7))]);
                }
#pragma unroll
                for (int i = 0; i < 4; ++i)
#pragma unroll
                    for (int j = 0; j < 2; ++j)
                        O[i][j] = __builtin_amdgcn_mfma_f32_16x16x32_bf16(pa[i], vb[j], O[i][j], 0, 0, 0);
            }
            __syncthreads();
        }
    }

    if constexpr (PHASE == 1) {
#pragma unroll
        for (int i = 0; i < 4; ++i)
#pragma unroll
            for (int reg = 0; reg < 4; ++reg) {
                float v = rsum[i][reg];
                v += __shfl_xor(v, 1); v += __shfl_xor(v, 2);
                v += __shfl_xor(v, 4); v += __shfl_xor(v, 8);
                if ((l & 15) == 0)
                    atomicAdd(&rowsum_out[h * B + qt * 128 + wr * 64 + i * 16 + (l >> 4) * 4 + reg], v);
            }
    } else {
        for (int i = tid; i < 512; i += 256)
            atomicAdd(&colsum[h * B + ct * 512 + i], cs[i]);
#pragma unroll
        for (int i = 0; i < 4; ++i)
#pragma unroll
            for (int j = 0; j < 2; ++j)
#pragma unroll
                for (int reg = 0; reg < 4; ++reg) {
                    int qrow = wr * 64 + i * 16 + (l >> 4) * 4 + reg;
                    ovp[((size_t)ct * B + qt * 128 + qrow) * DIM + h * 64 + wc * 32 + j * 16 + (l & 15)] =
                        O[i][j][reg];
                }
    }
}

// ---------------------------------------------------------------------------
// K5: maskfix with fused per-block top-5 (deterministic redundant scan).
// grid (32 rt, 8 h).
// ---------------------------------------------------------------------------
__global__ __launch_bounds__(256) void maskfix_topk(float* __restrict__ attn,
                                                    const float* __restrict__ v_f32,
                                                    const float* __restrict__ colsum,
                                                    const float* __restrict__ ovp,
                                                    unsigned short* __restrict__ ovbf) {
    int rt = blockIdx.x;
    int h = blockIdx.y;
    int tid = threadIdx.x;
    __shared__ float v[B];
    __shared__ float bv[256];
    __shared__ int bi[256];
    __shared__ float Pl[5][64];
    __shared__ float Vl[5][64];
    __shared__ int tix[5];
    for (int i = tid; i < B; i += 256) v[i] = colsum[h * B + i];
    __syncthreads();
    for (int it = 0; it < 5; ++it) {
        float best = -1e30f;
        int bidx = 0;
        for (int i = tid; i < B; i += 256) {
            float x = v[i];
            if (x > best || (x == best && i < bidx)) { best = x; bidx = i; }
        }
        bv[tid] = best; bi[tid] = bidx;
        __syncthreads();
        for (int s = 128; s > 0; s >>= 1) {
            if (tid < s) {
                if (bv[tid + s] > bv[tid] ||
                    (bv[tid + s] == bv[tid] && bi[tid + s] < bi[tid])) {
                    bv[tid] = bv[tid + s]; bi[tid] = bi[tid + s];
                }
            }
            __syncthreads();
        }
        if (tid == 0) { tix[it] = bi[0]; v[bi[0]] = -1e30f; }
        __syncthreads();
    }
    size_t abase = (size_t)h * B * B + (size_t)(rt * 64) * B;
    for (int t = tid; t < 320; t += 256) {
        int i = t / 64, q = t % 64;
        Pl[i][q] = attn[abase + (size_t)q * B + tix[i]];
        Vl[i][q] = v_f32[(size_t)tix[i] * DIM + h * 64 + q];
    }
    __syncthreads();
    for (int t = tid; t < 320; t += 256) {
        int i = t / 64, q = t % 64;
        attn[abase + (size_t)q * B + tix[i]] = 0.f;
    }
    int tx = tid % 16, ty = tid / 16;
    float corr[4][4] = {};
#pragma unroll
    for (int i = 0; i < 5; ++i)
#pragma unroll
        for (int a = 0; a < 4; ++a)
#pragma unroll
            for (int b2 = 0; b2 < 4; ++b2)
                corr[a][b2] += Pl[i][ty * 4 + a] * Vl[i][tx * 4 + b2];
#pragma unroll
    for (int a = 0; a < 4; ++a) {
        size_t row = (size_t)(rt * 64 + ty * 4 + a);
        size_t col = h * 64 + tx * 4;
        float4 s0 = *(const float4*)(ovp + ((size_t)0 * B + row) * DIM + col);
        float4 s1 = *(const float4*)(ovp + ((size_t)1 * B + row) * DIM + col);
        float4 s2 = *(const float4*)(ovp + ((size_t)2 * B + row) * DIM + col);
        float4 s3 = *(const float4*)(ovp + ((size_t)3 * B + row) * DIM + col);
        ushort4 u;
        u.x = f2bf(s0.x + s1.x + s2.x + s3.x - corr[a][0]);
        u.y = f2bf(s0.y + s1.y + s2.y + s3.y - corr[a][1]);
        u.z = f2bf(s0.z + s1.z + s2.z + s3.z - corr[a][2]);
        u.w = f2bf(s0.w + s1.w + s2.w + s3.w - corr[a][3]);
        *(ushort4*)(ovbf + row * DIM + col) = u;
    }
}

// ---------------------------------------------------------------------------
// K7: y = ov @ W_proj^T + b_proj via bf16 MFMA; fused BN partial sums.
// ---------------------------------------------------------------------------
__global__ __launch_bounds__(256) void proj_gemm_mfma(const unsigned short* __restrict__ ovbf,
                                                      const unsigned short* __restrict__ wpbf,
                                                      const float* __restrict__ bproj,
                                                      float* __restrict__ y,
                                                      float* __restrict__ sums,
                                                      float* __restrict__ ssums) {
    int nt = blockIdx.x;   // 0..7
    int mt = blockIdx.y;   // 0..15
    __shared__ uint4 Ax[128 * 8];
    __shared__ uint4 Bw[64 * 8];
    __shared__ float sb[64];
    __shared__ float qb[64];
    int tid = threadIdx.x;
    int l = tid & 63, wid = tid >> 6;
    int wr = wid >> 1, wc = wid & 1;
    if (tid < 64) { sb[tid] = 0.f; qb[tid] = 0.f; }
    const uint4* a4 = (const uint4*)ovbf;
    const uint4* b4 = (const uint4*)wpbf;
    f32x4 acc[4][2];
#pragma unroll
    for (int i = 0; i < 4; ++i)
#pragma unroll
        for (int j = 0; j < 2; ++j) acc[i][j] = (f32x4){0.f, 0.f, 0.f, 0.f};

    for (int kt = 0; kt < 8; ++kt) {
        int kg = kt * 8;
#pragma unroll
        for (int it = 0; it < 4; ++it) {
            int chunk = it * 256 + tid;
            int row = chunk >> 3, slot = chunk & 7;
            Ax[row * 8 + (slot ^ (row & 7))] = a4[(size_t)(mt * 128 + row) * 64 + kg + slot];
        }
#pragma unroll
        for (int it = 0; it < 2; ++it) {
            int chunk = it * 256 + tid;
            int row = chunk >> 3, slot = chunk & 7;
            Bw[row * 8 + (slot ^ (row & 7))] = b4[(size_t)(nt * 64 + row) * 64 + kg + slot];
        }
        __syncthreads();
#pragma unroll
        for (int km = 0; km < 2; ++km) {
            int gsel = km * 4 + (l >> 4);
            bf16x8 a[4], b[2];
#pragma unroll
            for (int i = 0; i < 4; ++i) {
                int row = wr * 64 + i * 16 + (l & 15);
                a[i] = __builtin_bit_cast(bf16x8, Ax[row * 8 + (gsel ^ (row & 7))]);
            }
#pragma unroll
            for (int j = 0; j < 2; ++j) {
                int row = wc * 32 + j * 16 + (l & 15);
                b[j] = __builtin_bit_cast(bf16x8, Bw[row * 8 + (gsel ^ (row & 7))]);
            }
#pragma unroll
            for (int i = 0; i < 4; ++i)
#pragma unroll
                for (int j = 0; j < 2; ++j)
                    acc[i][j] = __builtin_amdgcn_mfma_f32_16x16x32_bf16(a[i], b[j], acc[i][j], 0, 0, 0);
        }
        __syncthreads();
    }
    float ls[2] = {0.f, 0.f};
    float lq[2] = {0.f, 0.f};
#pragma unroll
    for (int i = 0; i < 4; ++i)
#pragma unroll
        for (int j = 0; j < 2; ++j) {
            int col = nt * 64 + wc * 32 + j * 16 + (l & 15);
            float bp = bproj[col];
#pragma unroll
            for (int reg = 0; reg < 4; ++reg) {
                int row = mt * 128 + wr * 64 + i * 16 + (l >> 4) * 4 + reg;
                float c = acc[i][j][reg] + bp;
                y[(size_t)row * DIM + col] = c;
                ls[j] += c; lq[j] += c * c;
            }
        }
#pragma unroll
    for (int j = 0; j < 2; ++j) {
        atomicAdd(&sb[wc * 32 + j * 16 + (l & 15)], ls[j]);
        atomicAdd(&qb[wc * 32 + j * 16 + (l & 15)], lq[j]);
    }
    __syncthreads();
    if (tid < 64) {
        atomicAdd(&sums[nt * 64 + tid], sb[tid]);
        atomicAdd(&ssums[nt * 64 + tid], qb[tid]);
    }
}

// ---------------------------------------------------------------------------
// K9: out = relu(gamma*(y-mean)*rstd + beta); mean/rstd from sums inline
// ---------------------------------------------------------------------------
__global__ __launch_bounds__(256) void bn_apply(const float* __restrict__ y,
                                                const float* __restrict__ sums,
                                                const float* __restrict__ ssums,
                                                const float* __restrict__ gamma,
                                                const float* __restrict__ beta,
                                                float* __restrict__ out) {
    int t = blockIdx.x * 256 + threadIdx.x;
    int c4 = (t % 128) * 4;
    size_t r = t / 128;
    if (r >= B) return;
    float4 s = *(const float4*)(sums + c4);
    float4 q = *(const float4*)(ssums + c4);
    float4 m, rs;
    m.x = s.x * (1.0f / B); m.y = s.y * (1.0f / B);
    m.z = s.z * (1.0f / B); m.w = s.w * (1.0f / B);
    rs.x = rsqrtf(q.x * (1.0f / B) - m.x * m.x + 1e-5f);
    rs.y = rsqrtf(q.y * (1.0f / B) - m.y * m.y + 1e-5f);
    rs.z = rsqrtf(q.z * (1.0f / B) - m.z * m.z + 1e-5f);
    rs.w = rsqrtf(q.w * (1.0f / B) - m.w * m.w + 1e-5f);
    float4 v = *(const float4*)(y + r * DIM + c4);
    float4 g = *(const float4*)(gamma + c4);
    float4 bt = *(const float4*)(beta + c4);
    float4 o;
    o.x = fmaxf(0.f, g.x * (v.x - m.x) * rs.x + bt.x);
    o.y = fmaxf(0.f, g.y * (v.y - m.y) * rs.y + bt.y);
    o.z = fmaxf(0.f, g.z * (v.z - m.z) * rs.z + bt.z);
    o.w = fmaxf(0.f, g.w * (v.w - m.w) * rs.w + bt.w);
    *(float4*)(out + r * DIM + c4) = o;
}

// ---------------------------------------------------------------------------
extern "C" void kernel_launch(void* const* d_in, const int* in_sizes, int n_in,
                              void* d_out, int out_size, void* d_ws, size_t ws_size,
                              hipStream_t stream) {
    const float* x = (const float*)d_in[0];
    const float* W_qkv = (const float*)d_in[1];
    const float* W_proj = (const float*)d_in[2];
    const float* b_proj = (const float*)d_in[3];
    const float* bn_gamma = (const float*)d_in[4];
    const float* bn_beta = (const float*)d_in[5];

    float* out0 = (float*)d_out;                         // [2048,512]
    float* attn = (float*)d_out + OUT0_ELEMS;            // [8,2048,2048]

    float* ws = (float*)d_ws;
    float* v_f32 = ws;                                   // 1,048,576 f
    float* ovp = v_f32 + OUT0_ELEMS;                     // 4,194,304 f
    float* y = ovp + 4 * OUT0_ELEMS;                     // 1,048,576 f
    // zero region (contiguous, one memset): rowsum, colsum, sums, ssums
    float* rowsum = y + OUT0_ELEMS;                      // 16,384 f
    float* colsum = rowsum + NH * B;                     // 16,384 f
    float* sums = colsum + NH * B;                       // 512 f
    float* ssums = sums + DIM;                           // 512 f
    unsigned short* qkbf = (unsigned short*)(ssums + DIM);       // B*1024 us
    unsigned short* vT = qkbf + (size_t)B * 1024;                // NH*HD*B us
    unsigned short* wpbf = vT + (size_t)NH * HD * B;             // 512*512 us
    unsigned short* ovbf = wpbf + (size_t)DIM * DIM;             // B*DIM us
    // xbf (2 MB) + wT (1.5 MB) alias ovp: consumed by gemm_qkv_mfma, which
    // completes before attn_pass<2> writes ovp.
    unsigned short* xbf = (unsigned short*)ovp;
    unsigned short* wT = xbf + (size_t)B * 512;

    hipMemsetAsync(rowsum, 0, (2 * NH * B + 2 * DIM) * sizeof(float), stream);

    prep_cast<<<1280 + 192, 256, 0, stream>>>(x, W_proj, W_qkv, xbf, wpbf, wT);
    gemm_qkv_mfma<<<dim3(QKVN / 64, B / 128), 256, 0, stream>>>(xbf, wT, v_f32, qkbf, vT);
    attn_pass<1><<<dim3(4, 16, NH), 256, 0, stream>>>(qkbf, vT, nullptr, rowsum,
                                                      attn, colsum, ovp);
    attn_pass<2><<<dim3(4, 16, NH), 256, 0, stream>>>(qkbf, vT, rowsum, nullptr,
                                                      attn, colsum, ovp);
    maskfix_topk<<<dim3(B / 64, NH), 256, 0, stream>>>(attn, v_f32, colsum, ovp, ovbf);
    proj_gemm_mfma<<<dim3(DIM / 64, B / 128), 256, 0, stream>>>(ovbf, wpbf, b_proj,
                                                                y, sums, ssums);
    bn_apply<<<(B * DIM / 4 + 255) / 256, 256, 0, stream>>>(y, sums, ssums,
                                                            bn_gamma, bn_beta, out0);
}